// Round 5
// baseline (433.671 us; speedup 1.0000x reference)
//
#include <hip/hip_runtime.h>

typedef __bf16 bf16_t;
typedef __bf16 bf16x2 __attribute__((ext_vector_type(2)));
typedef __bf16 bf16x4 __attribute__((ext_vector_type(4)));
typedef __bf16 bf16x8 __attribute__((ext_vector_type(8)));
typedef float  f32x4  __attribute__((ext_vector_type(4)));

#define NPIX 2048
#define NS   64
#define NK   8
#define NSAMP (NPIX*NS)          // 131072
#define NROWS (NSAMP*NK)         // 1048576
#define TROWS 64
#define NTILES (NROWS/TROWS)     // 16384
#define GRID   512
#define NIT    16                // 32 tiles/block = 16 A-tiles + 16 B-tiles
#define XSTR 104                 // 96 cols + 8 pad (bf16); stride 52 dw ≡ 20 mod 32: conflict-free, keeps b128
#define HSTR 132                 // 128 cols + 4 pad (bf16); stride 66 dw ≡ 2 mod 32:
                                 //   8B stores hit all 32 banks (was: even-only, 4 extra cy/store =
                                 //   the constant 3.175e7 SQ_LDS_BANK_CONFLICT). Rows now 8B-aligned
                                 //   -> H reads via 2x ds_read_b64 (also exactly-floor banks).

// packed-weight fragment bases (in bf16x8 units) — pack layout UNCHANGED:
// the B-fragment pack of W is element-identical to the A-fragment pack of W^T.
#define PK_W0 0
#define PK_W1 1536
#define PK_W2 3584
#define PK_WA 5632
#define PK_WR 6656
#define PK_TOT 7680

#define WS_AR_BYTES 122880       // float4 per sample after packed weights

// ---------------------------------------------------------------------------
// Pack W (row-major [KD,ND] fp32), bf16:
// elem e = ((t*KS + s)*64 + l)*8 + j  holds  W[s*32 + (l>>4)*8 + j][t*16 + (l&15)]
// Interpreted as A-fragment of W^T: A[m = l&15][k = s*32+(l>>4)*8+j] = W[k][m].
// ---------------------------------------------------------------------------
__global__ void pack_weights(const float* __restrict__ W0, const float* __restrict__ W1,
                             const float* __restrict__ W2, const float* __restrict__ Wa0,
                             const float* __restrict__ Wr0, bf16_t* __restrict__ dst0) {
  int tid = blockIdx.x * blockDim.x + threadIdx.x;
  if (tid >= PK_TOT * 8) return;
  const float* src; bf16_t* dst; int e, KD, ND, KS;
  if (tid < 12288)      { src = W0;  dst = dst0;         e = tid;         KD = 88;  ND = 128; KS = 3; }
  else if (tid < 28672) { src = W1;  dst = dst0 + 12288; e = tid - 12288; KD = 128; ND = 128; KS = 4; }
  else if (tid < 45056) { src = W2;  dst = dst0 + 28672; e = tid - 28672; KD = 128; ND = 128; KS = 4; }
  else if (tid < 53248) { src = Wa0; dst = dst0 + 45056; e = tid - 45056; KD = 128; ND = 64;  KS = 4; }
  else                  { src = Wr0; dst = dst0 + 53248; e = tid - 53248; KD = 128; ND = 64;  KS = 4; }
  int j = e & 7, l = (e >> 3) & 63, f = e >> 9;
  int s = f % KS, t = f / KS;
  int row = s * 32 + (l >> 4) * 8 + j;
  int col = t * 16 + (l & 15);
  float v = (row < KD) ? src[row * ND + col] : 0.f;
  dst[e] = (bf16_t)v;
}

__device__ __forceinline__ float lrelu(float v) { return fmaxf(v, 0.1f * v); }
__device__ __forceinline__ float sigmoidf(float x) { return 1.f / (1.f + __expf(-x)); }

// 16B logical load from an 8B-aligned HSTR-strided row: two ds_read_b64
// (compiler fuses to ds_read2_b64). Bank math at stride 66 dw: 2n+d -> floor.
__device__ __forceinline__ bf16x8 ld8(const bf16_t* p) {
  union { bf16x8 v; struct { bf16x4 lo; bf16x4 hi; } s; } u;
  u.s.lo = *(const bf16x4*)p;
  u.s.hi = *(const bf16x4*)(p + 4);
  return u.v;
}

// ---------------------------------------------------------------------------
// Round-11: BANK-CONFLICT FIX on the dual-stream pipeline.
// The constant SQ_LDS_BANK_CONFLICT=3.175e7 (22% of CU cycles) was located in
// the epilogue bf16x4 stores: HSTR=136 -> row stride 68 dw ≡ 4 mod 32 -> a
// quarter-wave's 8B stores hit only even banks (4n+d), 2x over-subscribed ->
// 4 extra cycles per store x 6.4M stores ≈ 26M ≈ the counter. HSTR=132 makes
// store banks 2n+d = all 32 exactly once (zero conflict); H-buffer reads drop
// from b128 to 2x b64 (rows 8B-aligned), which is also exactly-floor.
// Dual-stream phase schedule, persistent weights, bias-in-acc-init, setprio
// all unchanged from round-10.
// ---------------------------------------------------------------------------
__global__ __launch_bounds__(512, 4)
void nerf_main(const float* __restrict__ map_xyz, const float* __restrict__ map_feat,
               const int* __restrict__ ind, const float* __restrict__ sample_xyz,
               const float* __restrict__ b0g, const float* __restrict__ b1g,
               const float* __restrict__ b2g, const float* __restrict__ ba0g,
               const float* __restrict__ wa1g, const float* __restrict__ ba1g,
               const float* __restrict__ br0g, const float* __restrict__ wr1g,
               const float* __restrict__ br1g, const bf16_t* __restrict__ wpack,
               float* __restrict__ ar_out)
{
  __shared__ __align__(16) bf16_t sH0[TROWS * HSTR];    // rotating H buffer
  __shared__ __align__(16) bf16_t sH1[TROWS * HSTR];    // rotating H buffer
  __shared__ __align__(16) bf16_t sX[TROWS * XSTR];     // X, time-shared A/B
  __shared__ __align__(16) bf16_t sFS[16 * HSTR];       // feat_s (rows 8..15 zero)
  __shared__ __align__(16) bf16_t sAR[16 * HSTR];       // [r|a] (rows 8..15 zero)
  __shared__ __align__(16) bf16_t sFB[2048];            // finals A-frags
  __shared__ __align__(16) float sWtA[TROWS], sWtB[TROWS];
  __shared__ float sWsA[8], sWsB[8];
  __shared__ __align__(16) float sB0[128], sB1[128], sB2[128], sBH[128], sFBv[4];

  const int tid = threadIdx.x;
  const int wid = tid >> 6, l = tid & 63;
  const int q = l >> 4, n = l & 15;
  const int sr = tid >> 3, sp = tid & 7;   // staging thread coords

  // ---- ALL weights persistent as A-fragments (60 VGPRs) ----
  const bf16x8* pk = (const bf16x8*)wpack;
  bf16x8 w0f[3], w1f[4], w2f[4], hdf[4];
#pragma unroll
  for (int s = 0; s < 3; s++) w0f[s] = pk[PK_W0 + (wid * 3 + s) * 64 + l];
#pragma unroll
  for (int s = 0; s < 4; s++) w1f[s] = pk[PK_W1 + (wid * 4 + s) * 64 + l];
#pragma unroll
  for (int s = 0; s < 4; s++) w2f[s] = pk[PK_W2 + (wid * 4 + s) * 64 + l];
#pragma unroll
  for (int s = 0; s < 4; s++)
    hdf[s] = pk[(wid < 4 ? PK_WA : PK_WR) + ((wid & 3) * 4 + s) * 64 + l];

  // ---- phase ops (lambdas; buffer pointers passed per call-site) ----
  auto COMMIT = [&](int tile, bf16_t* X, float* wtbuf) {
    const int m = tile * TROWS + sr;
    const int idx = ind[m];
    const float4* fp = (const float4*)(map_feat + (size_t)idx * 64 + sp * 8);
    float4 f0 = fp[0], f1 = fp[1];
    bf16x8 v;
    v[0] = (bf16_t)f0.x; v[1] = (bf16_t)f0.y; v[2] = (bf16_t)f0.z; v[3] = (bf16_t)f0.w;
    v[4] = (bf16_t)f1.x; v[5] = (bf16_t)f1.y; v[6] = (bf16_t)f1.z; v[7] = (bf16_t)f1.w;
    *(bf16x8*)(X + sr * XSTR + sp * 8) = v;
    const int g = m >> 3;
    if (sp < 6) {
      const int d = sp >> 1;
      float o = sample_xyz[g * 3 + d] - map_xyz[idx * 3 + d];
      float s1 = __sinf(o), c1 = __cosf(o);
      float s2 = 2.f * s1 * c1, c2 = 1.f - 2.f * s1 * s1;
      float s4 = 2.f * s2 * c2, c4 = 1.f - 2.f * s2 * s2;
      float s8 = 2.f * s4 * c4, c8 = 1.f - 2.f * s4 * s4;
      bf16x4 e;
      if (sp & 1) { e[0] = (bf16_t)c1; e[1] = (bf16_t)c2; e[2] = (bf16_t)c4; e[3] = (bf16_t)c8; }
      else        { e[0] = (bf16_t)s1; e[1] = (bf16_t)s2; e[2] = (bf16_t)s4; e[3] = (bf16_t)s8; }
      *(bf16x4*)(X + sr * XSTR + 64 + d * 8 + (sp & 1) * 4) = e;
    } else if (sp == 6) {
      bf16x8 z = {};
      *(bf16x8*)(X + sr * XSTR + 88) = z;   // pad cols 88..95 (zero k-rows)
    } else {
      float ox = sample_xyz[g * 3 + 0] - map_xyz[idx * 3 + 0];
      float oy = sample_xyz[g * 3 + 1] - map_xyz[idx * 3 + 1];
      float oz = sample_xyz[g * 3 + 2] - map_xyz[idx * 3 + 2];
      wtbuf[sr] = __expf(-10.f * sqrtf(ox * ox + oy * oy + oz * oz));
    }
  };

  auto L0 = [&](const bf16_t* X, bf16_t* Hout) {
    f32x4 bi = *(const f32x4*)(sB0 + wid * 16 + q * 4);
    f32x4 acc[4] = {bi, bi, bi, bi};
    __builtin_amdgcn_s_setprio(1);
#pragma unroll
    for (int st = 0; st < 4; st++)
#pragma unroll
      for (int s = 0; s < 3; s++) {
        bf16x8 b = *(const bf16x8*)(X + (st * 16 + n) * XSTR + s * 32 + q * 8);
        acc[st] = __builtin_amdgcn_mfma_f32_16x16x32_bf16(w0f[s], b, acc[st], 0, 0, 0);
      }
    __builtin_amdgcn_s_setprio(0);
#pragma unroll
    for (int st = 0; st < 4; st++) {
      bf16x4 o;
      o[0] = (bf16_t)lrelu(acc[st][0]);
      o[1] = (bf16_t)lrelu(acc[st][1]);
      o[2] = (bf16_t)lrelu(acc[st][2]);
      o[3] = (bf16_t)lrelu(acc[st][3]);
      *(bf16x4*)(Hout + (st * 16 + n) * HSTR + wid * 16 + q * 4) = o;
    }
  };

  auto LAYER = [&](const bf16_t* Hin, bf16_t* Hout, const bf16x8* wf, const float* bg) {
    f32x4 bi = *(const f32x4*)(bg + wid * 16 + q * 4);
    f32x4 acc[4] = {bi, bi, bi, bi};
    __builtin_amdgcn_s_setprio(1);
#pragma unroll
    for (int st = 0; st < 4; st++)
#pragma unroll
      for (int s = 0; s < 4; s++) {
        bf16x8 b = ld8(Hin + (st * 16 + n) * HSTR + s * 32 + q * 8);
        acc[st] = __builtin_amdgcn_mfma_f32_16x16x32_bf16(wf[s], b, acc[st], 0, 0, 0);
      }
    __builtin_amdgcn_s_setprio(0);
#pragma unroll
    for (int st = 0; st < 4; st++) {
      bf16x4 o;
      o[0] = (bf16_t)lrelu(acc[st][0]);
      o[1] = (bf16_t)lrelu(acc[st][1]);
      o[2] = (bf16_t)lrelu(acc[st][2]);
      o[3] = (bf16_t)lrelu(acc[st][3]);
      *(bf16x4*)(Hout + (st * 16 + n) * HSTR + wid * 16 + q * 4) = o;
    }
  };

  auto KRED = [&](const bf16_t* Hin, const float* wt, const float* ws, bf16_t* FS) {
    int g = tid >> 6;
    int c = (tid & 63) * 2;
    float a0 = 0.f, a1 = 0.f;
#pragma unroll
    for (int k = 0; k < 8; k++) {
      float wk = wt[g * 8 + k];
      unsigned u = *(const unsigned*)(Hin + (g * 8 + k) * HSTR + c);
      a0 += wk * __uint_as_float(u << 16);
      a1 += wk * __uint_as_float(u & 0xffff0000u);
    }
    float inv = 1.f / ws[g];
    bf16x2 fo;
    fo[0] = (bf16_t)(a0 * inv);
    fo[1] = (bf16_t)(a1 * inv);
    *(bf16x2*)(FS + g * HSTR + c) = fo;
  };

  auto HEADS = [&](const bf16_t* FS, bf16_t* AR) {
    f32x4 ha = *(const f32x4*)(sBH + wid * 16 + q * 4);
    __builtin_amdgcn_s_setprio(1);
#pragma unroll
    for (int s = 0; s < 4; s++) {
      bf16x8 b = ld8(FS + n * HSTR + s * 32 + q * 8);
      ha = __builtin_amdgcn_mfma_f32_16x16x32_bf16(hdf[s], b, ha, 0, 0, 0);
    }
    __builtin_amdgcn_s_setprio(0);
    if (n < 8) {   // valid sample groups; rows 8..15 of sAR stay zero
      const int base = (wid < 4) ? 64 : 0;    // a-vals high, r-vals low
      bf16x4 o;
      o[0] = (bf16_t)lrelu(ha[0]);
      o[1] = (bf16_t)lrelu(ha[1]);
      o[2] = (bf16_t)lrelu(ha[2]);
      o[3] = (bf16_t)lrelu(ha[3]);
      *(bf16x4*)(AR + n * HSTR + base + (wid & 3) * 16 + q * 4) = o;
    }
  };

  auto FINALS = [&](int tile) {
    if (wid == 0) {
      f32x4 c = *(const f32x4*)sFBv;
#pragma unroll
      for (int s = 0; s < 4; s++) {
        bf16x8 a = *(const bf16x8*)(sFB + (s * 64 + l) * 8);
        bf16x8 b = ld8(sAR + n * HSTR + s * 32 + q * 8);
        c = __builtin_amdgcn_mfma_f32_16x16x32_bf16(a, b, c, 0, 0, 0);
      }
      if (q == 0 && n < 8) {
        float4 o;
        o.x = sigmoidf(c[0]);
        o.y = sigmoidf(c[1]);
        o.z = sigmoidf(c[2]);
        o.w = sigmoidf(c[3]);
        ((float4*)ar_out)[tile * 8 + n] = o;
      }
    }
  };

  // ---- one-time LDS init ----
  for (int i = tid; i < 8 * HSTR; i += 512) {
    sFS[8 * HSTR + i] = (bf16_t)0.f;
    sAR[8 * HSTR + i] = (bf16_t)0.f;
  }
  {  // finals A-frags: A[m][k] = Wfin[k][m]; m<3 -> Wr1 (k<64), m==3 -> Wa1 (k>=64)
    int e0 = tid * 4;
    int jb = e0 & 7, ll = (e0 >> 3) & 63, s = e0 >> 9;
    int m = ll & 15;
#pragma unroll
    for (int ii = 0; ii < 4; ii++) {
      int k = s * 32 + (ll >> 4) * 8 + jb + ii;
      float v = 0.f;
      if (k < 64)  { if (m < 3) v = wr1g[k * 3 + m]; }
      else         { if (m == 3) v = wa1g[k - 64]; }
      sFB[e0 + ii] = (bf16_t)v;
    }
  }
  if (tid < 128)      sB0[tid] = b0g[tid];
  else if (tid < 256) sB1[tid - 128] = b1g[tid - 128];
  else if (tid < 384) sB2[tid - 256] = b2g[tid - 256];
  else { int t = tid - 384; sBH[t] = (t < 64) ? ba0g[t] : br0g[t - 64]; }
  if (tid < 4) sFBv[tid] = (tid < 3) ? br1g[tid] : ba1g[0];
  __syncthreads();

  // ---- pipeline: A tiles j=2it, B tiles j=2it+1 (j = tile index / GRID) ----
  for (int it = 0; it <= NIT; ++it) {
    const bool a_on = (it < NIT);
    const bool b_on = (it > 0);
    const int tA  = (int)blockIdx.x + (2 * it) * GRID;
    const int tAp = (int)blockIdx.x + (2 * it - 2) * GRID;
    const int tB  = (int)blockIdx.x + (2 * it + 1) * GRID;
    const int tBp = (int)blockIdx.x + (2 * it - 1) * GRID;

    // ---- p1: commitA(sX) | L2B(H0->H1) | finalsA ----
    if (a_on) COMMIT(tA, sX, sWtA);
    if (b_on) LAYER(sH0, sH1, w2f, sB2);
    if (b_on) FINALS(tAp);
    __syncthreads();

    // ---- p2: L0A(sX->H0) | kredB(H1) | sWsA ----
    if (a_on) L0(sX, sH0);
    if (b_on) KRED(sH1, sWtB, sWsB, sFS);
    if (a_on && tid < 8) {
      float ss = 0.f;
#pragma unroll
      for (int k = 0; k < 8; k++) ss += sWtA[tid * 8 + k];
      sWsA[tid] = ss;
    }
    __syncthreads();

    // ---- p3: L1A(H0->H1) | headsB(sFS->sAR) ----
    if (a_on) LAYER(sH0, sH1, w1f, sB1);
    if (b_on) HEADS(sFS, sAR);
    __syncthreads();

    // ---- p4: L2A(H1->H0) | commitB(sX) | finalsB ----
    if (a_on) COMMIT(tB, sX, sWtB);
    if (a_on) LAYER(sH1, sH0, w2f, sB2);
    if (b_on) FINALS(tBp);
    __syncthreads();

    if (it == NIT) break;   // drain complete (uniform exit)

    // ---- p5: kredA(H0) | L0B(sX->H1) | sWsB ----
    L0(sX, sH1);
    KRED(sH0, sWtA, sWsA, sFS);
    if (tid < 8) {
      float ss = 0.f;
#pragma unroll
      for (int k = 0; k < 8; k++) ss += sWtB[tid * 8 + k];
      sWsB[tid] = ss;
    }
    __syncthreads();

    // ---- p6: headsA(sFS->sAR) | L1B(H1->H0) ----
    LAYER(sH1, sH0, w1f, sB1);
    HEADS(sFS, sAR);
    __syncthreads();
  }
}

// ---------------------------------------------------------------------------
// Volume rendering: one wave per ray; lane s holds sample s. All cross-lane
// ops execute with FULL exec mask (round-2/3 lesson: masked-source bpermute).
// ---------------------------------------------------------------------------
__global__ __launch_bounds__(512)
void render_kernel(const float* __restrict__ ar, const float* __restrict__ dcam,
                   float* __restrict__ out) {
  int ray = blockIdx.x * 8 + (threadIdx.x >> 6);
  int s = threadIdx.x & 63;
  float4 v = ((const float4*)ar)[ray * 64 + s];
  float alpha = v.w;
  float t = 1.f - alpha + 1e-10f;
  float p = t;
#pragma unroll
  for (int d = 1; d < 64; d <<= 1) {
    float o = __shfl_up(p, d);
    if (s >= d) p *= o;
  }
  float pm1 = __shfl_up(p, 1);                // unconditional
  float T = (s == 0) ? 1.f : pm1;             // exclusive product
  float bl = alpha * T;
  float dist = 1.f + 1.25f * dcam[ray * 64 + s];
  float cr = v.x * bl, cg = v.y * bl, cb = v.z * bl, cd = dist * bl, ca = bl;
#pragma unroll
  for (int d = 32; d > 0; d >>= 1) {
    cr += __shfl_xor(cr, d);
    cg += __shfl_xor(cg, d);
    cb += __shfl_xor(cb, d);
    cd += __shfl_xor(cd, d);
    ca += __shfl_xor(ca, d);
  }
  if (s == 0) {
    out[ray * 5 + 0] = cr; out[ray * 5 + 1] = cg; out[ray * 5 + 2] = cb;
    out[ray * 5 + 3] = cd; out[ray * 5 + 4] = ca;
  }
}

// ---------------------------------------------------------------------------
extern "C" void kernel_launch(void* const* d_in, const int* in_sizes, int n_in,
                              void* d_out, int out_size, void* d_ws, size_t ws_size,
                              hipStream_t stream) {
  const float* map_xyz    = (const float*)d_in[0];
  const float* map_feat   = (const float*)d_in[1];
  const int*   ind        = (const int*)d_in[2];
  const float* sample_xyz = (const float*)d_in[3];
  const float* dist_cam   = (const float*)d_in[4];
  const float* W0  = (const float*)d_in[5];
  const float* b0  = (const float*)d_in[6];
  const float* W1  = (const float*)d_in[7];
  const float* b1  = (const float*)d_in[8];
  const float* W2  = (const float*)d_in[9];
  const float* b2  = (const float*)d_in[10];
  const float* Wa0 = (const float*)d_in[11];
  const float* ba0 = (const float*)d_in[12];
  const float* Wa1 = (const float*)d_in[13];
  const float* ba1 = (const float*)d_in[14];
  const float* Wr0 = (const float*)d_in[15];
  const float* br0 = (const float*)d_in[16];
  const float* Wr1 = (const float*)d_in[17];
  const float* br1 = (const float*)d_in[18];

  bf16_t* wpack = (bf16_t*)d_ws;
  float*  ar    = (float*)((char*)d_ws + WS_AR_BYTES);

  pack_weights<<<240, 256, 0, stream>>>(W0, W1, W2, Wa0, Wr0, wpack);
  nerf_main<<<GRID, 512, 0, stream>>>(map_xyz, map_feat, ind, sample_xyz,
                                      b0, b1, b2, ba0, Wa1, ba1, br0, Wr1, br1,
                                      wpack, ar);
  render_kernel<<<256, 512, 0, stream>>>(ar, dist_cam, (float*)d_out);
}

// Round 6
// 426.792 us; speedup vs baseline: 1.0161x; 1.0161x over previous
//
#include <hip/hip_runtime.h>

typedef __bf16 bf16_t;
typedef __bf16 bf16x2 __attribute__((ext_vector_type(2)));
typedef __bf16 bf16x4 __attribute__((ext_vector_type(4)));
typedef __bf16 bf16x8 __attribute__((ext_vector_type(8)));
typedef float  f32x4  __attribute__((ext_vector_type(4)));

#define NPIX 2048
#define NS   64
#define NK   8
#define NSAMP (NPIX*NS)          // 131072
#define NROWS (NSAMP*NK)         // 1048576
#define TROWS 64
#define NTILES (NROWS/TROWS)     // 16384
#define GRID   256               // 1 block/CU (VGPR ~170): 64 tiles/block
#define NIT    32                // = 32 A-tiles + 32 B-tiles per block
#define XSTR 104                 // 96 cols + 8 pad (bf16), rows 16B-aligned
#define HSTR 136                 // 128 cols + 8 pad; b128-everywhere (round-5 lesson:
                                 //   LDS time tracks instruction count; b128 = max bytes/instr;
                                 //   the 4-way store conflict is absorbed slack)

// packed-weight fragment bases (in bf16x8 units) — pack layout UNCHANGED:
// the B-fragment pack of W is element-identical to the A-fragment pack of W^T.
#define PK_W0 0
#define PK_W1 1536
#define PK_W2 3584
#define PK_WA 5632
#define PK_WR 6656
#define PK_TOT 7680

#define WS_AR_BYTES 122880       // float4 per sample after packed weights

// ---------------------------------------------------------------------------
// Pack W (row-major [KD,ND] fp32), bf16:
// elem e = ((t*KS + s)*64 + l)*8 + j  holds  W[s*32 + (l>>4)*8 + j][t*16 + (l&15)]
// Interpreted as A-fragment of W^T: A[m = l&15][k = s*32+(l>>4)*8+j] = W[k][m].
// ---------------------------------------------------------------------------
__global__ void pack_weights(const float* __restrict__ W0, const float* __restrict__ W1,
                             const float* __restrict__ W2, const float* __restrict__ Wa0,
                             const float* __restrict__ Wr0, bf16_t* __restrict__ dst0) {
  int tid = blockIdx.x * blockDim.x + threadIdx.x;
  if (tid >= PK_TOT * 8) return;
  const float* src; bf16_t* dst; int e, KD, ND, KS;
  if (tid < 12288)      { src = W0;  dst = dst0;         e = tid;         KD = 88;  ND = 128; KS = 3; }
  else if (tid < 28672) { src = W1;  dst = dst0 + 12288; e = tid - 12288; KD = 128; ND = 128; KS = 4; }
  else if (tid < 45056) { src = W2;  dst = dst0 + 28672; e = tid - 28672; KD = 128; ND = 128; KS = 4; }
  else if (tid < 53248) { src = Wa0; dst = dst0 + 45056; e = tid - 45056; KD = 128; ND = 64;  KS = 4; }
  else                  { src = Wr0; dst = dst0 + 53248; e = tid - 53248; KD = 128; ND = 64;  KS = 4; }
  int j = e & 7, l = (e >> 3) & 63, f = e >> 9;
  int s = f % KS, t = f / KS;
  int row = s * 32 + (l >> 4) * 8 + j;
  int col = t * 16 + (l & 15);
  float v = (row < KD) ? src[row * ND + col] : 0.f;
  dst[e] = (bf16_t)v;
}

__device__ __forceinline__ float lrelu(float v) { return fmaxf(v, 0.1f * v); }
__device__ __forceinline__ float sigmoidf(float x) { return 1.f / (1.f + __expf(-x)); }

// ---------------------------------------------------------------------------
// Round-12: HALVED LDS READ AMPLIFICATION.
// Round-5's inverse experiment (b128->2xb64: +instructions, -conflicts, +16%
// time) proved the wall is LDS instruction/byte throughput: with 16-col waves
// every wave reads the ENTIRE layer input (8x amplification) — ~420KB/tile =
// ~90% of the per-tile cycle budget. New decomposition: 8 waves = 4 col-groups
// (wc: 32 out-cols) x 2 sample-halves (ws: 32 samples). Same MFMA count/acc/
// stores per wave; B-frags shared across the 2 m-tiles and only half the
// samples read -> L1/L2 reads 16->8 b128/wave, L0 12->6, bytes halved.
// Cost: 26 persistent weight frags (104 VGPR) -> ~170 VGPR -> 1 block/CU
// (launch_bounds(512,2), GRID 256). Dual-stream phase schedule kept for
// within-block pipe diversity. HSTR back to 136, all-b128.
// ---------------------------------------------------------------------------
__global__ __launch_bounds__(512, 2)
void nerf_main(const float* __restrict__ map_xyz, const float* __restrict__ map_feat,
               const int* __restrict__ ind, const float* __restrict__ sample_xyz,
               const float* __restrict__ b0g, const float* __restrict__ b1g,
               const float* __restrict__ b2g, const float* __restrict__ ba0g,
               const float* __restrict__ wa1g, const float* __restrict__ ba1g,
               const float* __restrict__ br0g, const float* __restrict__ wr1g,
               const float* __restrict__ br1g, const bf16_t* __restrict__ wpack,
               float* __restrict__ ar_out)
{
  __shared__ __align__(16) bf16_t sH0[TROWS * HSTR];    // rotating H buffer
  __shared__ __align__(16) bf16_t sH1[TROWS * HSTR];    // rotating H buffer
  __shared__ __align__(16) bf16_t sX[TROWS * XSTR];     // X, time-shared A/B
  __shared__ __align__(16) bf16_t sFS[16 * HSTR];       // feat_s (rows 8..15 zero)
  __shared__ __align__(16) bf16_t sAR[16 * HSTR];       // [r|a] (rows 8..15 zero)
  __shared__ __align__(16) bf16_t sFB[2048];            // finals A-frags
  __shared__ __align__(16) float sWtA[TROWS], sWtB[TROWS];
  __shared__ float sWsA[8], sWsB[8];
  __shared__ __align__(16) float sB0[128], sB1[128], sB2[128], sBH[128], sFBv[4];

  const int tid = threadIdx.x;
  const int wid = tid >> 6, l = tid & 63;
  const int q = l >> 4, n = l & 15;
  const int wc = wid & 3, ws = wid >> 2;   // col-group (32 cols), sample-half (32 rows)
  const int sr = tid >> 3, sp = tid & 7;   // staging thread coords

  // ---- persistent weights: 26 frags = 104 VGPR ----
  const bf16x8* pk = (const bf16x8*)wpack;
  bf16x8 w0f[6], w1f[8], w2f[8], hdf[4];
#pragma unroll
  for (int m = 0; m < 2; m++) {
#pragma unroll
    for (int s = 0; s < 3; s++) w0f[m * 3 + s] = pk[PK_W0 + ((2 * wc + m) * 3 + s) * 64 + l];
#pragma unroll
    for (int s = 0; s < 4; s++) w1f[m * 4 + s] = pk[PK_W1 + ((2 * wc + m) * 4 + s) * 64 + l];
#pragma unroll
    for (int s = 0; s < 4; s++) w2f[m * 4 + s] = pk[PK_W2 + ((2 * wc + m) * 4 + s) * 64 + l];
  }
#pragma unroll
  for (int s = 0; s < 4; s++)
    hdf[s] = pk[(wid < 4 ? PK_WA : PK_WR) + ((wid & 3) * 4 + s) * 64 + l];

  // ---- phase ops ----
  auto COMMIT = [&](int tile, bf16_t* X, float* wtbuf) {
    const int m = tile * TROWS + sr;
    const int idx = ind[m];
    const float4* fp = (const float4*)(map_feat + (size_t)idx * 64 + sp * 8);
    float4 f0 = fp[0], f1 = fp[1];
    bf16x8 v;
    v[0] = (bf16_t)f0.x; v[1] = (bf16_t)f0.y; v[2] = (bf16_t)f0.z; v[3] = (bf16_t)f0.w;
    v[4] = (bf16_t)f1.x; v[5] = (bf16_t)f1.y; v[6] = (bf16_t)f1.z; v[7] = (bf16_t)f1.w;
    *(bf16x8*)(X + sr * XSTR + sp * 8) = v;
    const int g = m >> 3;
    if (sp < 6) {
      const int d = sp >> 1;
      float o = sample_xyz[g * 3 + d] - map_xyz[idx * 3 + d];
      float s1 = __sinf(o), c1 = __cosf(o);
      float s2 = 2.f * s1 * c1, c2 = 1.f - 2.f * s1 * s1;
      float s4 = 2.f * s2 * c2, c4 = 1.f - 2.f * s2 * s2;
      float s8 = 2.f * s4 * c4, c8 = 1.f - 2.f * s4 * s4;
      bf16x4 e;
      if (sp & 1) { e[0] = (bf16_t)c1; e[1] = (bf16_t)c2; e[2] = (bf16_t)c4; e[3] = (bf16_t)c8; }
      else        { e[0] = (bf16_t)s1; e[1] = (bf16_t)s2; e[2] = (bf16_t)s4; e[3] = (bf16_t)s8; }
      *(bf16x4*)(X + sr * XSTR + 64 + d * 8 + (sp & 1) * 4) = e;
    } else if (sp == 6) {
      bf16x8 z = {};
      *(bf16x8*)(X + sr * XSTR + 88) = z;   // pad cols 88..95 (zero k-rows)
    } else {
      float ox = sample_xyz[g * 3 + 0] - map_xyz[idx * 3 + 0];
      float oy = sample_xyz[g * 3 + 1] - map_xyz[idx * 3 + 1];
      float oz = sample_xyz[g * 3 + 2] - map_xyz[idx * 3 + 2];
      wtbuf[sr] = __expf(-10.f * sqrtf(ox * ox + oy * oy + oz * oz));
    }
  };

  // L0 (K=96): wave computes cols [wc*32, wc*32+32) x samples [ws*32, ws*32+32)
  auto L0 = [&](const bf16_t* X, bf16_t* Hout) {
    f32x4 acc[2][2];
#pragma unroll
    for (int m = 0; m < 2; m++) {
      f32x4 bi = *(const f32x4*)(sB0 + wc * 32 + m * 16 + q * 4);
      acc[m][0] = bi; acc[m][1] = bi;
    }
    __builtin_amdgcn_s_setprio(1);
#pragma unroll
    for (int st = 0; st < 2; st++) {
      bf16x8 b[3];
#pragma unroll
      for (int s = 0; s < 3; s++)
        b[s] = *(const bf16x8*)(X + (ws * 32 + st * 16 + n) * XSTR + s * 32 + q * 8);
#pragma unroll
      for (int m = 0; m < 2; m++)
#pragma unroll
        for (int s = 0; s < 3; s++)
          acc[m][st] = __builtin_amdgcn_mfma_f32_16x16x32_bf16(w0f[m * 3 + s], b[s], acc[m][st], 0, 0, 0);
    }
    __builtin_amdgcn_s_setprio(0);
#pragma unroll
    for (int m = 0; m < 2; m++)
#pragma unroll
      for (int st = 0; st < 2; st++) {
        bf16x4 o;
        o[0] = (bf16_t)lrelu(acc[m][st][0]);
        o[1] = (bf16_t)lrelu(acc[m][st][1]);
        o[2] = (bf16_t)lrelu(acc[m][st][2]);
        o[3] = (bf16_t)lrelu(acc[m][st][3]);
        *(bf16x4*)(Hout + (ws * 32 + st * 16 + n) * HSTR + wc * 32 + m * 16 + q * 4) = o;
      }
  };

  auto LAYER = [&](const bf16_t* Hin, bf16_t* Hout, const bf16x8* wf, const float* bg) {
    f32x4 acc[2][2];
#pragma unroll
    for (int m = 0; m < 2; m++) {
      f32x4 bi = *(const f32x4*)(bg + wc * 32 + m * 16 + q * 4);
      acc[m][0] = bi; acc[m][1] = bi;
    }
    __builtin_amdgcn_s_setprio(1);
#pragma unroll
    for (int st = 0; st < 2; st++) {
      bf16x8 b[4];
#pragma unroll
      for (int s = 0; s < 4; s++)
        b[s] = *(const bf16x8*)(Hin + (ws * 32 + st * 16 + n) * HSTR + s * 32 + q * 8);
#pragma unroll
      for (int m = 0; m < 2; m++)
#pragma unroll
        for (int s = 0; s < 4; s++)
          acc[m][st] = __builtin_amdgcn_mfma_f32_16x16x32_bf16(wf[m * 4 + s], b[s], acc[m][st], 0, 0, 0);
    }
    __builtin_amdgcn_s_setprio(0);
#pragma unroll
    for (int m = 0; m < 2; m++)
#pragma unroll
      for (int st = 0; st < 2; st++) {
        bf16x4 o;
        o[0] = (bf16_t)lrelu(acc[m][st][0]);
        o[1] = (bf16_t)lrelu(acc[m][st][1]);
        o[2] = (bf16_t)lrelu(acc[m][st][2]);
        o[3] = (bf16_t)lrelu(acc[m][st][3]);
        *(bf16x4*)(Hout + (ws * 32 + st * 16 + n) * HSTR + wc * 32 + m * 16 + q * 4) = o;
      }
  };

  auto KRED = [&](const bf16_t* Hin, const float* wt, const float* ws_, bf16_t* FS) {
    int g = tid >> 6;
    int c = (tid & 63) * 2;
    float a0 = 0.f, a1 = 0.f;
#pragma unroll
    for (int k = 0; k < 8; k++) {
      float wk = wt[g * 8 + k];
      unsigned u = *(const unsigned*)(Hin + (g * 8 + k) * HSTR + c);
      a0 += wk * __uint_as_float(u << 16);
      a1 += wk * __uint_as_float(u & 0xffff0000u);
    }
    float inv = 1.f / ws_[g];
    bf16x2 fo;
    fo[0] = (bf16_t)(a0 * inv);
    fo[1] = (bf16_t)(a1 * inv);
    *(bf16x2*)(FS + g * HSTR + c) = fo;
  };

  auto HEADS = [&](const bf16_t* FS, bf16_t* AR) {
    f32x4 ha = *(const f32x4*)(sBH + wid * 16 + q * 4);
    __builtin_amdgcn_s_setprio(1);
#pragma unroll
    for (int s = 0; s < 4; s++) {
      bf16x8 b = *(const bf16x8*)(FS + n * HSTR + s * 32 + q * 8);
      ha = __builtin_amdgcn_mfma_f32_16x16x32_bf16(hdf[s], b, ha, 0, 0, 0);
    }
    __builtin_amdgcn_s_setprio(0);
    if (n < 8) {   // valid sample groups; rows 8..15 of sAR stay zero
      const int base = (wid < 4) ? 64 : 0;    // a-vals high, r-vals low
      bf16x4 o;
      o[0] = (bf16_t)lrelu(ha[0]);
      o[1] = (bf16_t)lrelu(ha[1]);
      o[2] = (bf16_t)lrelu(ha[2]);
      o[3] = (bf16_t)lrelu(ha[3]);
      *(bf16x4*)(AR + n * HSTR + base + (wid & 3) * 16 + q * 4) = o;
    }
  };

  auto FINALS = [&](int tile) {
    if (wid == 0) {
      f32x4 c = *(const f32x4*)sFBv;
#pragma unroll
      for (int s = 0; s < 4; s++) {
        bf16x8 a = *(const bf16x8*)(sFB + (s * 64 + l) * 8);
        bf16x8 b = *(const bf16x8*)(sAR + n * HSTR + s * 32 + q * 8);
        c = __builtin_amdgcn_mfma_f32_16x16x32_bf16(a, b, c, 0, 0, 0);
      }
      if (q == 0 && n < 8) {
        float4 o;
        o.x = sigmoidf(c[0]);
        o.y = sigmoidf(c[1]);
        o.z = sigmoidf(c[2]);
        o.w = sigmoidf(c[3]);
        ((float4*)ar_out)[tile * 8 + n] = o;
      }
    }
  };

  // ---- one-time LDS init ----
  for (int i = tid; i < 8 * HSTR; i += 512) {
    sFS[8 * HSTR + i] = (bf16_t)0.f;
    sAR[8 * HSTR + i] = (bf16_t)0.f;
  }
  {  // finals A-frags: A[m][k] = Wfin[k][m]; m<3 -> Wr1 (k<64), m==3 -> Wa1 (k>=64)
    int e0 = tid * 4;
    int jb = e0 & 7, ll = (e0 >> 3) & 63, s = e0 >> 9;
    int m = ll & 15;
#pragma unroll
    for (int ii = 0; ii < 4; ii++) {
      int k = s * 32 + (ll >> 4) * 8 + jb + ii;
      float v = 0.f;
      if (k < 64)  { if (m < 3) v = wr1g[k * 3 + m]; }
      else         { if (m == 3) v = wa1g[k - 64]; }
      sFB[e0 + ii] = (bf16_t)v;
    }
  }
  if (tid < 128)      sB0[tid] = b0g[tid];
  else if (tid < 256) sB1[tid - 128] = b1g[tid - 128];
  else if (tid < 384) sB2[tid - 256] = b2g[tid - 256];
  else { int t = tid - 384; sBH[t] = (t < 64) ? ba0g[t] : br0g[t - 64]; }
  if (tid < 4) sFBv[tid] = (tid < 3) ? br1g[tid] : ba1g[0];
  __syncthreads();

  // ---- dual-stream pipeline: A tiles j=2it, B tiles j=2it+1 ----
  for (int it = 0; it <= NIT; ++it) {
    const bool a_on = (it < NIT);
    const bool b_on = (it > 0);
    const int tA  = (int)blockIdx.x + (2 * it) * GRID;
    const int tAp = (int)blockIdx.x + (2 * it - 2) * GRID;
    const int tB  = (int)blockIdx.x + (2 * it + 1) * GRID;
    const int tBp = (int)blockIdx.x + (2 * it - 1) * GRID;

    // ---- p1: commitA(sX) | L2B(H0->H1) | finalsA ----
    if (a_on) COMMIT(tA, sX, sWtA);
    if (b_on) LAYER(sH0, sH1, w2f, sB2);
    if (b_on) FINALS(tAp);
    __syncthreads();

    // ---- p2: L0A(sX->H0) | kredB(H1) | sWsA ----
    if (a_on) L0(sX, sH0);
    if (b_on) KRED(sH1, sWtB, sWsB, sFS);
    if (a_on && tid < 8) {
      float ss = 0.f;
#pragma unroll
      for (int k = 0; k < 8; k++) ss += sWtA[tid * 8 + k];
      sWsA[tid] = ss;
    }
    __syncthreads();

    // ---- p3: L1A(H0->H1) | headsB(sFS->sAR) ----
    if (a_on) LAYER(sH0, sH1, w1f, sB1);
    if (b_on) HEADS(sFS, sAR);
    __syncthreads();

    // ---- p4: L2A(H1->H0) | commitB(sX) | finalsB ----
    if (a_on) COMMIT(tB, sX, sWtB);
    if (a_on) LAYER(sH1, sH0, w2f, sB2);
    if (b_on) FINALS(tBp);
    __syncthreads();

    if (it == NIT) break;   // drain complete (uniform exit)

    // ---- p5: kredA(H0) | L0B(sX->H1) | sWsB ----
    L0(sX, sH1);
    KRED(sH0, sWtA, sWsA, sFS);
    if (tid < 8) {
      float ss = 0.f;
#pragma unroll
      for (int k = 0; k < 8; k++) ss += sWtB[tid * 8 + k];
      sWsB[tid] = ss;
    }
    __syncthreads();

    // ---- p6: headsA(sFS->sAR) | L1B(H1->H0) ----
    LAYER(sH1, sH0, w1f, sB1);
    HEADS(sFS, sAR);
    __syncthreads();
  }
}

// ---------------------------------------------------------------------------
// Volume rendering: one wave per ray; lane s holds sample s. All cross-lane
// ops execute with FULL exec mask (round-2/3 lesson: masked-source bpermute).
// ---------------------------------------------------------------------------
__global__ __launch_bounds__(512)
void render_kernel(const float* __restrict__ ar, const float* __restrict__ dcam,
                   float* __restrict__ out) {
  int ray = blockIdx.x * 8 + (threadIdx.x >> 6);
  int s = threadIdx.x & 63;
  float4 v = ((const float4*)ar)[ray * 64 + s];
  float alpha = v.w;
  float t = 1.f - alpha + 1e-10f;
  float p = t;
#pragma unroll
  for (int d = 1; d < 64; d <<= 1) {
    float o = __shfl_up(p, d);
    if (s >= d) p *= o;
  }
  float pm1 = __shfl_up(p, 1);                // unconditional
  float T = (s == 0) ? 1.f : pm1;             // exclusive product
  float bl = alpha * T;
  float dist = 1.f + 1.25f * dcam[ray * 64 + s];
  float cr = v.x * bl, cg = v.y * bl, cb = v.z * bl, cd = dist * bl, ca = bl;
#pragma unroll
  for (int d = 32; d > 0; d >>= 1) {
    cr += __shfl_xor(cr, d);
    cg += __shfl_xor(cg, d);
    cb += __shfl_xor(cb, d);
    cd += __shfl_xor(cd, d);
    ca += __shfl_xor(ca, d);
  }
  if (s == 0) {
    out[ray * 5 + 0] = cr; out[ray * 5 + 1] = cg; out[ray * 5 + 2] = cb;
    out[ray * 5 + 3] = cd; out[ray * 5 + 4] = ca;
  }
}

// ---------------------------------------------------------------------------
extern "C" void kernel_launch(void* const* d_in, const int* in_sizes, int n_in,
                              void* d_out, int out_size, void* d_ws, size_t ws_size,
                              hipStream_t stream) {
  const float* map_xyz    = (const float*)d_in[0];
  const float* map_feat   = (const float*)d_in[1];
  const int*   ind        = (const int*)d_in[2];
  const float* sample_xyz = (const float*)d_in[3];
  const float* dist_cam   = (const float*)d_in[4];
  const float* W0  = (const float*)d_in[5];
  const float* b0  = (const float*)d_in[6];
  const float* W1  = (const float*)d_in[7];
  const float* b1  = (const float*)d_in[8];
  const float* W2  = (const float*)d_in[9];
  const float* b2  = (const float*)d_in[10];
  const float* Wa0 = (const float*)d_in[11];
  const float* ba0 = (const float*)d_in[12];
  const float* Wa1 = (const float*)d_in[13];
  const float* ba1 = (const float*)d_in[14];
  const float* Wr0 = (const float*)d_in[15];
  const float* br0 = (const float*)d_in[16];
  const float* Wr1 = (const float*)d_in[17];
  const float* br1 = (const float*)d_in[18];

  bf16_t* wpack = (bf16_t*)d_ws;
  float*  ar    = (float*)((char*)d_ws + WS_AR_BYTES);

  pack_weights<<<240, 256, 0, stream>>>(W0, W1, W2, Wa0, Wr0, wpack);
  nerf_main<<<GRID, 512, 0, stream>>>(map_xyz, map_feat, ind, sample_xyz,
                                      b0, b1, b2, ba0, Wa1, ba1, br0, Wr1, br1,
                                      wpack, ar);
  render_kernel<<<256, 512, 0, stream>>>(ar, dist_cam, (float*)d_out);
}

// Round 7
// 398.862 us; speedup vs baseline: 1.0873x; 1.0700x over previous
//
#include <hip/hip_runtime.h>

typedef __bf16 bf16_t;
typedef __bf16 bf16x2 __attribute__((ext_vector_type(2)));
typedef __bf16 bf16x4 __attribute__((ext_vector_type(4)));
typedef __bf16 bf16x8 __attribute__((ext_vector_type(8)));
typedef float  f32x4  __attribute__((ext_vector_type(4)));

#define NPIX 2048
#define NS   64
#define NK   8
#define NSAMP (NPIX*NS)          // 131072
#define NROWS (NSAMP*NK)         // 1048576
#define TROWS 64
#define NTILES (NROWS/TROWS)     // 16384
#define GRID   512               // 2 blocks/CU; block owns 32 CONSECUTIVE tiles = 4 pixels
#define NIT    16                // stream A: tiles 0..15 of chunk; stream B: 16..31
#define XSTR 104                 // 96 cols + 8 pad (bf16), rows 16B-aligned
#define HSTR 136                 // 128 cols + 8 pad (R4 champion value; R5 proved b128-count
                                 //   beats conflict-avoidance, so keep b128-everywhere)

// packed-weight fragment bases (in bf16x8 units)
#define PK_W0 0
#define PK_W1 1536
#define PK_W2 3584
#define PK_WA 5632
#define PK_WR 6656
#define PK_TOT 7680

// ---------------------------------------------------------------------------
// Pack W (row-major [KD,ND] fp32), bf16:
// elem e = ((t*KS + s)*64 + l)*8 + j  holds  W[s*32 + (l>>4)*8 + j][t*16 + (l&15)]
// Interpreted as A-fragment of W^T: A[m = l&15][k = s*32+(l>>4)*8+j] = W[k][m].
// ---------------------------------------------------------------------------
__global__ void pack_weights(const float* __restrict__ W0, const float* __restrict__ W1,
                             const float* __restrict__ W2, const float* __restrict__ Wa0,
                             const float* __restrict__ Wr0, bf16_t* __restrict__ dst0) {
  int tid = blockIdx.x * blockDim.x + threadIdx.x;
  if (tid >= PK_TOT * 8) return;
  const float* src; bf16_t* dst; int e, KD, ND, KS;
  if (tid < 12288)      { src = W0;  dst = dst0;         e = tid;         KD = 88;  ND = 128; KS = 3; }
  else if (tid < 28672) { src = W1;  dst = dst0 + 12288; e = tid - 12288; KD = 128; ND = 128; KS = 4; }
  else if (tid < 45056) { src = W2;  dst = dst0 + 28672; e = tid - 28672; KD = 128; ND = 128; KS = 4; }
  else if (tid < 53248) { src = Wa0; dst = dst0 + 45056; e = tid - 45056; KD = 128; ND = 64;  KS = 4; }
  else                  { src = Wr0; dst = dst0 + 53248; e = tid - 53248; KD = 128; ND = 64;  KS = 4; }
  int j = e & 7, l = (e >> 3) & 63, f = e >> 9;
  int s = f % KS, t = f / KS;
  int row = s * 32 + (l >> 4) * 8 + j;
  int col = t * 16 + (l & 15);
  float v = (row < KD) ? src[row * ND + col] : 0.f;
  dst[e] = (bf16_t)v;
}

__device__ __forceinline__ float lrelu(float v) { return fmaxf(v, 0.1f * v); }
__device__ __forceinline__ float sigmoidf(float x) { return 1.f / (1.f + __expf(-x)); }

// ---------------------------------------------------------------------------
// Round-13: R4 champion + FUSED RENDERING + ADDRESS HOISTING.
// R5/R6 post-mortems: LDS bytes/conflicts are NOT the wall (killing either
// lost time); the kernel is latency/issue-bound; waves matter. So: restore the
// R4 structure exactly (2 blocks/CU, 16-col waves, dual-stream 6-phase), and
// attack (a) the ~155us of non-nerf time: block->tile mapping is now CHUNKED
// (block b = tiles b*32..b*32+31 = pixels 4b..4b+3; stream A first 16, B last
// 16 -> each stream sees its pixels' samples IN ORDER), FINALS banks each
// tile's 8 samples in a small LDS pixel buffer and every 8th tile wave 0 runs
// the volume-render scan in-kernel, writing out[] directly — render kernel,
// its launch, and the 2MB ar round-trip are gone; (b) VALU overhead: all
// phase reads/stores go through one per-wave base pointer + compile-time
// offsets (ds offset immediates), targeting the ~2x VALU instruction surplus.
// ---------------------------------------------------------------------------
__global__ __launch_bounds__(512, 4)
void nerf_main(const float* __restrict__ map_xyz, const float* __restrict__ map_feat,
               const int* __restrict__ ind, const float* __restrict__ sample_xyz,
               const float* __restrict__ dcam,
               const float* __restrict__ b0g, const float* __restrict__ b1g,
               const float* __restrict__ b2g, const float* __restrict__ ba0g,
               const float* __restrict__ wa1g, const float* __restrict__ ba1g,
               const float* __restrict__ br0g, const float* __restrict__ wr1g,
               const float* __restrict__ br1g, const bf16_t* __restrict__ wpack,
               float* __restrict__ out)
{
  __shared__ __align__(16) bf16_t sH0[TROWS * HSTR];    // rotating H buffer
  __shared__ __align__(16) bf16_t sH1[TROWS * HSTR];    // rotating H buffer
  __shared__ __align__(16) bf16_t sX[TROWS * XSTR];     // X, time-shared A/B
  __shared__ __align__(16) bf16_t sFS[16 * HSTR];       // feat_s (rows 8..15 zero)
  __shared__ __align__(16) bf16_t sAR[16 * HSTR];       // [r|a] (rows 8..15 zero)
  __shared__ __align__(16) bf16_t sFB[2048];            // finals A-frags
  __shared__ __align__(16) float4 sPix[2 * 64];         // per-stream pixel bank (wave-0 private)
  __shared__ __align__(16) float sWtA[TROWS], sWtB[TROWS];
  __shared__ float sWsA[8], sWsB[8];
  __shared__ __align__(16) float sB0[128], sB1[128], sB2[128], sBH[128], sFBv[4];

  const int tid = threadIdx.x;
  const int wid = tid >> 6, l = tid & 63;
  const int q = l >> 4, n = l & 15;
  const int sr = tid >> 3, sp = tid & 7;   // staging thread coords

  // ---- ALL weights persistent as A-fragments (60 VGPRs) ----
  const bf16x8* pk = (const bf16x8*)wpack;
  bf16x8 w0f[3], w1f[4], w2f[4], hdf[4];
#pragma unroll
  for (int s = 0; s < 3; s++) w0f[s] = pk[PK_W0 + (wid * 3 + s) * 64 + l];
#pragma unroll
  for (int s = 0; s < 4; s++) w1f[s] = pk[PK_W1 + (wid * 4 + s) * 64 + l];
#pragma unroll
  for (int s = 0; s < 4; s++) w2f[s] = pk[PK_W2 + (wid * 4 + s) * 64 + l];
#pragma unroll
  for (int s = 0; s < 4; s++)
    hdf[s] = pk[(wid < 4 ? PK_WA : PK_WR) + ((wid & 3) * 4 + s) * 64 + l];

  // ---- phase ops ----
  auto COMMIT = [&](int tile, bf16_t* X, float* wtbuf) {
    const int m = tile * TROWS + sr;
    const int idx = ind[m];
    const float4* fp = (const float4*)(map_feat + (size_t)idx * 64 + sp * 8);
    float4 f0 = fp[0], f1 = fp[1];
    bf16x8 v;
    v[0] = (bf16_t)f0.x; v[1] = (bf16_t)f0.y; v[2] = (bf16_t)f0.z; v[3] = (bf16_t)f0.w;
    v[4] = (bf16_t)f1.x; v[5] = (bf16_t)f1.y; v[6] = (bf16_t)f1.z; v[7] = (bf16_t)f1.w;
    *(bf16x8*)(X + sr * XSTR + sp * 8) = v;
    const int g = m >> 3;
    if (sp < 6) {
      const int d = sp >> 1;
      float o = sample_xyz[g * 3 + d] - map_xyz[idx * 3 + d];
      float s1 = __sinf(o), c1 = __cosf(o);
      float s2 = 2.f * s1 * c1, c2 = 1.f - 2.f * s1 * s1;
      float s4 = 2.f * s2 * c2, c4 = 1.f - 2.f * s2 * s2;
      float s8 = 2.f * s4 * c4, c8 = 1.f - 2.f * s4 * s4;
      bf16x4 e;
      if (sp & 1) { e[0] = (bf16_t)c1; e[1] = (bf16_t)c2; e[2] = (bf16_t)c4; e[3] = (bf16_t)c8; }
      else        { e[0] = (bf16_t)s1; e[1] = (bf16_t)s2; e[2] = (bf16_t)s4; e[3] = (bf16_t)s8; }
      *(bf16x4*)(X + sr * XSTR + 64 + d * 8 + (sp & 1) * 4) = e;
    } else if (sp == 6) {
      bf16x8 z = {};
      *(bf16x8*)(X + sr * XSTR + 88) = z;   // pad cols 88..95 (zero k-rows)
    } else {
      float ox = sample_xyz[g * 3 + 0] - map_xyz[idx * 3 + 0];
      float oy = sample_xyz[g * 3 + 1] - map_xyz[idx * 3 + 1];
      float oz = sample_xyz[g * 3 + 2] - map_xyz[idx * 3 + 2];
      wtbuf[sr] = __expf(-10.f * sqrtf(ox * ox + oy * oy + oz * oz));
    }
  };

  auto L0 = [&](const bf16_t* X, bf16_t* Hout) {
    f32x4 bi = *(const f32x4*)(sB0 + wid * 16 + q * 4);
    f32x4 acc[4] = {bi, bi, bi, bi};
    const bf16_t* rb = X + n * XSTR + q * 8;          // hoisted base; (st,s) are
    bf16_t* wb = Hout + n * HSTR + wid * 16 + q * 4;  //   compile-time offsets
    __builtin_amdgcn_s_setprio(1);
#pragma unroll
    for (int st = 0; st < 4; st++)
#pragma unroll
      for (int s = 0; s < 3; s++) {
        bf16x8 b = *(const bf16x8*)(rb + st * 16 * XSTR + s * 32);
        acc[st] = __builtin_amdgcn_mfma_f32_16x16x32_bf16(w0f[s], b, acc[st], 0, 0, 0);
      }
    __builtin_amdgcn_s_setprio(0);
#pragma unroll
    for (int st = 0; st < 4; st++) {
      bf16x4 o;
      o[0] = (bf16_t)lrelu(acc[st][0]);
      o[1] = (bf16_t)lrelu(acc[st][1]);
      o[2] = (bf16_t)lrelu(acc[st][2]);
      o[3] = (bf16_t)lrelu(acc[st][3]);
      *(bf16x4*)(wb + st * 16 * HSTR) = o;
    }
  };

  auto LAYER = [&](const bf16_t* Hin, bf16_t* Hout, const bf16x8* wf, const float* bg) {
    f32x4 bi = *(const f32x4*)(bg + wid * 16 + q * 4);
    f32x4 acc[4] = {bi, bi, bi, bi};
    const bf16_t* rb = Hin + n * HSTR + q * 8;
    bf16_t* wb = Hout + n * HSTR + wid * 16 + q * 4;
    __builtin_amdgcn_s_setprio(1);
#pragma unroll
    for (int st = 0; st < 4; st++)
#pragma unroll
      for (int s = 0; s < 4; s++) {
        bf16x8 b = *(const bf16x8*)(rb + st * 16 * HSTR + s * 32);
        acc[st] = __builtin_amdgcn_mfma_f32_16x16x32_bf16(wf[s], b, acc[st], 0, 0, 0);
      }
    __builtin_amdgcn_s_setprio(0);
#pragma unroll
    for (int st = 0; st < 4; st++) {
      bf16x4 o;
      o[0] = (bf16_t)lrelu(acc[st][0]);
      o[1] = (bf16_t)lrelu(acc[st][1]);
      o[2] = (bf16_t)lrelu(acc[st][2]);
      o[3] = (bf16_t)lrelu(acc[st][3]);
      *(bf16x4*)(wb + st * 16 * HSTR) = o;
    }
  };

  auto KRED = [&](const bf16_t* Hin, const float* wt, const float* ws_, bf16_t* FS) {
    int g = tid >> 6;
    int c = (tid & 63) * 2;
    const bf16_t* kb = Hin + g * 8 * HSTR + c;        // hoisted base; k offset const
    float a0 = 0.f, a1 = 0.f;
#pragma unroll
    for (int k = 0; k < 8; k++) {
      float wk = wt[g * 8 + k];
      unsigned u = *(const unsigned*)(kb + k * HSTR);
      a0 += wk * __uint_as_float(u << 16);
      a1 += wk * __uint_as_float(u & 0xffff0000u);
    }
    float inv = 1.f / ws_[g];
    bf16x2 fo;
    fo[0] = (bf16_t)(a0 * inv);
    fo[1] = (bf16_t)(a1 * inv);
    *(bf16x2*)(FS + g * HSTR + c) = fo;
  };

  auto HEADS = [&](const bf16_t* FS, bf16_t* AR) {
    f32x4 ha = *(const f32x4*)(sBH + wid * 16 + q * 4);
    const bf16_t* rb = FS + n * HSTR + q * 8;
    __builtin_amdgcn_s_setprio(1);
#pragma unroll
    for (int s = 0; s < 4; s++) {
      bf16x8 b = *(const bf16x8*)(rb + s * 32);
      ha = __builtin_amdgcn_mfma_f32_16x16x32_bf16(hdf[s], b, ha, 0, 0, 0);
    }
    __builtin_amdgcn_s_setprio(0);
    if (n < 8) {   // valid sample groups; rows 8..15 of sAR stay zero
      const int base = (wid < 4) ? 64 : 0;    // a-vals high, r-vals low
      bf16x4 o;
      o[0] = (bf16_t)lrelu(ha[0]);
      o[1] = (bf16_t)lrelu(ha[1]);
      o[2] = (bf16_t)lrelu(ha[2]);
      o[3] = (bf16_t)lrelu(ha[3]);
      *(bf16x4*)(AR + n * HSTR + base + (wid & 3) * 16 + q * 4) = o;
    }
  };

  // k = within-stream tile ordinal (0..15); st = stream (0=A,1=B); pix = pixel id.
  // Writes this tile's 8 samples to the LDS pixel bank; every 8th tile, runs the
  // volume-render scan across the banked 64 samples and writes out[pix*5..].
  // All LDS traffic here is wave-0-private -> no barriers needed.
  auto FINALS = [&](int k, int st, int pix) {
    if (wid == 0) {
      f32x4 c = *(const f32x4*)sFBv;
      const bf16_t* ab = sFB + l * 8;
      const bf16_t* rb = sAR + n * HSTR + q * 8;
#pragma unroll
      for (int s = 0; s < 4; s++) {
        bf16x8 a = *(const bf16x8*)(ab + s * 512);
        bf16x8 b = *(const bf16x8*)(rb + s * 32);
        c = __builtin_amdgcn_mfma_f32_16x16x32_bf16(a, b, c, 0, 0, 0);
      }
      float4* px = (float4*)sPix + st * 64;
      if (q == 0 && n < 8) {
        float4 o;
        o.x = sigmoidf(c[0]);
        o.y = sigmoidf(c[1]);
        o.z = sigmoidf(c[2]);
        o.w = sigmoidf(c[3]);
        px[(k & 7) * 8 + n] = o;
      }
      if ((k & 7) == 7) {   // pixel complete: render in-wave (64 lanes = 64 samples)
        float4 v = px[l];
        float dc = dcam[pix * 64 + l];
        float alpha = v.w;
        float p = 1.f - alpha + 1e-10f;
#pragma unroll
        for (int d = 1; d < 64; d <<= 1) {
          float o2 = __shfl_up(p, d);
          if (l >= d) p *= o2;
        }
        float pm1 = __shfl_up(p, 1);              // unconditional
        float T = (l == 0) ? 1.f : pm1;           // exclusive product
        float bl = alpha * T;
        float dist = 1.f + 1.25f * dc;
        float cr = v.x * bl, cg = v.y * bl, cb = v.z * bl, cd = dist * bl, ca = bl;
#pragma unroll
        for (int d = 32; d > 0; d >>= 1) {
          cr += __shfl_xor(cr, d);
          cg += __shfl_xor(cg, d);
          cb += __shfl_xor(cb, d);
          cd += __shfl_xor(cd, d);
          ca += __shfl_xor(ca, d);
        }
        if (l == 0) {
          out[pix * 5 + 0] = cr; out[pix * 5 + 1] = cg; out[pix * 5 + 2] = cb;
          out[pix * 5 + 3] = cd; out[pix * 5 + 4] = ca;
        }
      }
    }
  };

  // ---- one-time LDS init ----
  for (int i = tid; i < 8 * HSTR; i += 512) {
    sFS[8 * HSTR + i] = (bf16_t)0.f;
    sAR[8 * HSTR + i] = (bf16_t)0.f;
  }
  {  // finals A-frags: A[m][k] = Wfin[k][m]; m<3 -> Wr1 (k<64), m==3 -> Wa1 (k>=64)
    int e0 = tid * 4;
    int jb = e0 & 7, ll = (e0 >> 3) & 63, s = e0 >> 9;
    int m = ll & 15;
#pragma unroll
    for (int ii = 0; ii < 4; ii++) {
      int k = s * 32 + (ll >> 4) * 8 + jb + ii;
      float v = 0.f;
      if (k < 64)  { if (m < 3) v = wr1g[k * 3 + m]; }
      else         { if (m == 3) v = wa1g[k - 64]; }
      sFB[e0 + ii] = (bf16_t)v;
    }
  }
  if (tid < 128)      sB0[tid] = b0g[tid];
  else if (tid < 256) sB1[tid - 128] = b1g[tid - 128];
  else if (tid < 384) sB2[tid - 256] = b2g[tid - 256];
  else { int t = tid - 384; sBH[t] = (t < 64) ? ba0g[t] : br0g[t - 64]; }
  if (tid < 4) sFBv[tid] = (tid < 3) ? br1g[tid] : ba1g[0];
  __syncthreads();

  // ---- dual-stream pipeline over the block's 32-tile chunk ----
  const int base = (int)blockIdx.x * 32;   // tiles base..base+31 = pixels 4b..4b+3
  const int bP = (int)blockIdx.x * 4;

  for (int it = 0; it <= NIT; ++it) {
    const bool a_on = (it < NIT);
    const bool b_on = (it > 0);
    const int tA = base + it;            // stream A: tiles 0..15 of chunk (pixels bP, bP+1)
    const int tB = base + 16 + it;       // stream B: tiles 16..31 (pixels bP+2, bP+3)
    const int kp = it - 1;               // ordinal of the tile being FINALS'd

    // ---- p1: commitA(sX) | L2B(H0->H1) | finalsA ----
    if (a_on) COMMIT(tA, sX, sWtA);
    if (b_on) LAYER(sH0, sH1, w2f, sB2);
    if (b_on) FINALS(kp, 0, bP + (kp >> 3));
    __syncthreads();

    // ---- p2: L0A(sX->H0) | kredB(H1) | sWsA ----
    if (a_on) L0(sX, sH0);
    if (b_on) KRED(sH1, sWtB, sWsB, sFS);
    if (a_on && tid < 8) {
      float ss = 0.f;
#pragma unroll
      for (int k = 0; k < 8; k++) ss += sWtA[tid * 8 + k];
      sWsA[tid] = ss;
    }
    __syncthreads();

    // ---- p3: L1A(H0->H1) | headsB(sFS->sAR) ----
    if (a_on) LAYER(sH0, sH1, w1f, sB1);
    if (b_on) HEADS(sFS, sAR);
    __syncthreads();

    // ---- p4: L2A(H1->H0) | commitB(sX) | finalsB ----
    if (a_on) COMMIT(tB, sX, sWtB);
    if (a_on) LAYER(sH1, sH0, w2f, sB2);
    if (b_on) FINALS(kp, 1, bP + 2 + (kp >> 3));
    __syncthreads();

    if (it == NIT) break;   // drain complete (uniform exit)

    // ---- p5: kredA(H0) | L0B(sX->H1) | sWsB ----
    L0(sX, sH1);
    KRED(sH0, sWtA, sWsA, sFS);
    if (tid < 8) {
      float ss = 0.f;
#pragma unroll
      for (int k = 0; k < 8; k++) ss += sWtB[tid * 8 + k];
      sWsB[tid] = ss;
    }
    __syncthreads();

    // ---- p6: headsA(sFS->sAR) | L1B(H1->H0) ----
    LAYER(sH1, sH0, w1f, sB1);
    HEADS(sFS, sAR);
    __syncthreads();
  }
}

// ---------------------------------------------------------------------------
extern "C" void kernel_launch(void* const* d_in, const int* in_sizes, int n_in,
                              void* d_out, int out_size, void* d_ws, size_t ws_size,
                              hipStream_t stream) {
  const float* map_xyz    = (const float*)d_in[0];
  const float* map_feat   = (const float*)d_in[1];
  const int*   ind        = (const int*)d_in[2];
  const float* sample_xyz = (const float*)d_in[3];
  const float* dist_cam   = (const float*)d_in[4];
  const float* W0  = (const float*)d_in[5];
  const float* b0  = (const float*)d_in[6];
  const float* W1  = (const float*)d_in[7];
  const float* b1  = (const float*)d_in[8];
  const float* W2  = (const float*)d_in[9];
  const float* b2  = (const float*)d_in[10];
  const float* Wa0 = (const float*)d_in[11];
  const float* ba0 = (const float*)d_in[12];
  const float* Wa1 = (const float*)d_in[13];
  const float* ba1 = (const float*)d_in[14];
  const float* Wr0 = (const float*)d_in[15];
  const float* br0 = (const float*)d_in[16];
  const float* Wr1 = (const float*)d_in[17];
  const float* br1 = (const float*)d_in[18];

  bf16_t* wpack = (bf16_t*)d_ws;

  pack_weights<<<240, 256, 0, stream>>>(W0, W1, W2, Wa0, Wr0, wpack);
  nerf_main<<<GRID, 512, 0, stream>>>(map_xyz, map_feat, ind, sample_xyz, dist_cam,
                                      b0, b1, b2, ba0, Wa1, ba1, br0, Wr1, br1,
                                      wpack, (float*)d_out);
}

// Round 8
// 373.626 us; speedup vs baseline: 1.1607x; 1.0675x over previous
//
#include <hip/hip_runtime.h>

typedef __bf16 bf16_t;
typedef __bf16 bf16x2 __attribute__((ext_vector_type(2)));
typedef __bf16 bf16x4 __attribute__((ext_vector_type(4)));
typedef __bf16 bf16x8 __attribute__((ext_vector_type(8)));
typedef float  f32x4  __attribute__((ext_vector_type(4)));
typedef int    i32x4  __attribute__((ext_vector_type(4)));

#define NPIX 2048
#define NS   64
#define NK   8
#define NSAMP (NPIX*NS)          // 131072
#define NROWS (NSAMP*NK)         // 1048576
#define TROWS 64
#define NTILES (NROWS/TROWS)     // 16384
#define GRID   512
#define NIT    16                // 32 tiles/block = 16 A + 16 B (strided, champion)
#define XSTR 104                 // 96 cols + 8 pad (bf16), rows 16B-aligned
#define HSTR 136                 // bf16 H3 buffer (champion value)
#define QSTR 144                 // i8 H1/H2 rows: 144B = 16-aligned (b128-able), 36dw ≡ 4 mod 32 (2-way, free)

// packed bf16 weight fragment bases (in bf16x8 units) — unchanged
#define PK_W0 0
#define PK_W1 1536
#define PK_W2 3584
#define PK_WA 5632
#define PK_WR 6656
#define PK_TOT 7680

#define PKQ_OFF   122880         // byte offset of i8 W1/W2 packs in workspace
#define WS_AR_BYTES (122880 + 32768)   // ar now after the 2x16KB i8 packs

// ---- i8 quantization scales (analytic from input distributions; see theory) ----
#define SW_Q 300.0f              // W1/W2: xavier sigma=1/sqrt(128) -> max ~0.37; 127/0.423
#define S1_Q 62.0f               // H1 range 5.5*sigma(0.373) = 2.05
#define S2_Q 87.0f               // H2 range 5.5*sigma(0.265) = 1.46
#define DQ1S2 (S2_Q / (S1_Q * SW_Q))   // dequant L1 acc and requant to S2, fused (lrelu homogeneous)
#define DQ2   (1.0f / (S2_Q * SW_Q))   // dequant L2 acc to f32

// ---------------------------------------------------------------------------
// bf16 pack (unchanged; W1/W2 bf16 regions now unused but keep offsets stable)
// ---------------------------------------------------------------------------
__global__ void pack_weights(const float* __restrict__ W0, const float* __restrict__ W1,
                             const float* __restrict__ W2, const float* __restrict__ Wa0,
                             const float* __restrict__ Wr0, bf16_t* __restrict__ dst0) {
  int tid = blockIdx.x * blockDim.x + threadIdx.x;
  if (tid >= PK_TOT * 8) return;
  const float* src; bf16_t* dst; int e, KD, ND, KS;
  if (tid < 12288)      { src = W0;  dst = dst0;         e = tid;         KD = 88;  ND = 128; KS = 3; }
  else if (tid < 28672) { src = W1;  dst = dst0 + 12288; e = tid - 12288; KD = 128; ND = 128; KS = 4; }
  else if (tid < 45056) { src = W2;  dst = dst0 + 28672; e = tid - 28672; KD = 128; ND = 128; KS = 4; }
  else if (tid < 53248) { src = Wa0; dst = dst0 + 45056; e = tid - 45056; KD = 128; ND = 64;  KS = 4; }
  else                  { src = Wr0; dst = dst0 + 53248; e = tid - 53248; KD = 128; ND = 64;  KS = 4; }
  int j = e & 7, l = (e >> 3) & 63, f = e >> 9;
  int s = f % KS, t = f / KS;
  int row = s * 32 + (l >> 4) * 8 + j;
  int col = t * 16 + (l & 15);
  float v = (row < KD) ? src[row * ND + col] : 0.f;
  dst[e] = (bf16_t)v;
}

// ---------------------------------------------------------------------------
// i8 pack for W1/W2: A-fragment of W^T for mfma_i32_16x16x64_i8.
// elem e = ((t*2+s)*64 + l)*16 + j holds sat(round(W[k][c]*SW_Q)) with
// k = s*64 + (l>>4)*16 + j, c = t*16 + (l&15). Layout-agnostic by symmetry:
// B-side (activations) uses the IDENTICAL linear 16-byte k-chunk per lane-group,
// so any internal k-permutation of the instruction cancels A-vs-B.
// ---------------------------------------------------------------------------
__global__ void pack_w12_i8(const float* __restrict__ W1, const float* __restrict__ W2,
                            char* __restrict__ dstq) {
  int tid = blockIdx.x * blockDim.x + threadIdx.x;
  if (tid >= 2 * 16384) return;
  const float* src = (tid < 16384) ? W1 : W2;
  int e = tid & 16383;
  int j = e & 15, l = (e >> 4) & 63, f = e >> 10;
  int s = f & 1, t = f >> 1;
  int k = s * 64 + ((l >> 4) << 4) + j;
  int c = t * 16 + (l & 15);
  int iv = (int)rintf(src[k * 128 + c] * SW_Q);
  iv = iv > 127 ? 127 : (iv < -127 ? -127 : iv);
  dstq[tid] = (char)iv;
}

__device__ __forceinline__ float lrelu(float v) { return fmaxf(v, 0.1f * v); }
__device__ __forceinline__ float sigmoidf(float x) { return 1.f / (1.f + __expf(-x)); }

// ---------------------------------------------------------------------------
// Round-14: i8 K=64 MFMA for L1/L2 on the R4 champion structure.
// Wall model: LDS-instruction throughput bound (~68% busy + queueing); the
// VGPR pool blocks wider waves (R6), so the only instr cut is K-doubling:
// L1/L2 B-frag reads 16 -> 8 b128/wave/tile (-21% of LDS pipe load), W1/W2
// regs halve. Quantization confined to H1/H2 (X, L0, H3, KRED, heads, finals
// all stay bf16/f32); scales analytic with saturating clamp; requant folded
// into one fma via lrelu positive-homogeneity (b1 pre-scaled by S2 in LDS).
// Dual-stream 6-phase schedule, single shared buffers (liveness verified):
//   sX: Aw p1/Ar p2, Bw p4/Br p5;  sQ1: A p2->p3, B p5->p6;
//   sQ2: A p3->p4, B p6->p1';      sH3: A p4->p5, B p1->p2;
//   sFS: A p5->p6, B p2->p3;       sAR: A p6->p1', B p3->p4.
// ---------------------------------------------------------------------------
__global__ __launch_bounds__(512, 4)
void nerf_main(const float* __restrict__ map_xyz, const float* __restrict__ map_feat,
               const int* __restrict__ ind, const float* __restrict__ sample_xyz,
               const float* __restrict__ b0g, const float* __restrict__ b1g,
               const float* __restrict__ b2g, const float* __restrict__ ba0g,
               const float* __restrict__ wa1g, const float* __restrict__ ba1g,
               const float* __restrict__ br0g, const float* __restrict__ wr1g,
               const float* __restrict__ br1g, const bf16_t* __restrict__ wpack,
               float* __restrict__ ar_out)
{
  __shared__ __align__(16) bf16_t sX[TROWS * XSTR];     // X (bf16)
  __shared__ __align__(16) char   sQ1[TROWS * QSTR];    // H1 (i8)
  __shared__ __align__(16) char   sQ2[TROWS * QSTR];    // H2 (i8)
  __shared__ __align__(16) bf16_t sH3[TROWS * HSTR];    // H3 (bf16, for KRED)
  __shared__ __align__(16) bf16_t sFS[16 * HSTR];       // feat_s (rows 8..15 zero)
  __shared__ __align__(16) bf16_t sAR[16 * HSTR];       // [r|a] (rows 8..15 zero)
  __shared__ __align__(16) bf16_t sFB[2048];            // finals A-frags
  __shared__ __align__(16) float sWtA[TROWS], sWtB[TROWS];
  __shared__ float sWsA[8], sWsB[8];
  __shared__ __align__(16) float sB0[128], sB1[128], sB2[128], sBH[128], sFBv[4];

  const int tid = threadIdx.x;
  const int wid = tid >> 6, l = tid & 63;
  const int q = l >> 4, n = l & 15;
  const int sr = tid >> 3, sp = tid & 7;   // staging thread coords

  // ---- persistent weights: W0/heads bf16 A-frags, W1/W2 i8 A-frags ----
  const bf16x8* pk = (const bf16x8*)wpack;
  bf16x8 w0f[3], hdf[4];
#pragma unroll
  for (int s = 0; s < 3; s++) w0f[s] = pk[PK_W0 + (wid * 3 + s) * 64 + l];
#pragma unroll
  for (int s = 0; s < 4; s++)
    hdf[s] = pk[(wid < 4 ? PK_WA : PK_WR) + ((wid & 3) * 4 + s) * 64 + l];
  const i32x4* pq = (const i32x4*)((const char*)wpack + PKQ_OFF);
  i32x4 w1q[2], w2q[2];
#pragma unroll
  for (int s = 0; s < 2; s++) {
    w1q[s] = pq[(wid * 2 + s) * 64 + l];
    w2q[s] = pq[1024 + (wid * 2 + s) * 64 + l];
  }

  // ---- phase ops ----
  auto COMMIT = [&](int tile, bf16_t* X, float* wtbuf) {
    const int m = tile * TROWS + sr;
    const int idx = ind[m];
    const float4* fp = (const float4*)(map_feat + (size_t)idx * 64 + sp * 8);
    float4 f0 = fp[0], f1 = fp[1];
    bf16x8 v;
    v[0] = (bf16_t)f0.x; v[1] = (bf16_t)f0.y; v[2] = (bf16_t)f0.z; v[3] = (bf16_t)f0.w;
    v[4] = (bf16_t)f1.x; v[5] = (bf16_t)f1.y; v[6] = (bf16_t)f1.z; v[7] = (bf16_t)f1.w;
    *(bf16x8*)(X + sr * XSTR + sp * 8) = v;
    const int g = m >> 3;
    if (sp < 6) {
      const int d = sp >> 1;
      float o = sample_xyz[g * 3 + d] - map_xyz[idx * 3 + d];
      float s1 = __sinf(o), c1 = __cosf(o);
      float s2 = 2.f * s1 * c1, c2 = 1.f - 2.f * s1 * s1;
      float s4 = 2.f * s2 * c2, c4 = 1.f - 2.f * s2 * s2;
      float s8 = 2.f * s4 * c4, c8 = 1.f - 2.f * s4 * s4;
      bf16x4 e;
      if (sp & 1) { e[0] = (bf16_t)c1; e[1] = (bf16_t)c2; e[2] = (bf16_t)c4; e[3] = (bf16_t)c8; }
      else        { e[0] = (bf16_t)s1; e[1] = (bf16_t)s2; e[2] = (bf16_t)s4; e[3] = (bf16_t)s8; }
      *(bf16x4*)(X + sr * XSTR + 64 + d * 8 + (sp & 1) * 4) = e;
    } else if (sp == 6) {
      bf16x8 z = {};
      *(bf16x8*)(X + sr * XSTR + 88) = z;   // pad cols 88..95 (zero k-rows)
    } else {
      float ox = sample_xyz[g * 3 + 0] - map_xyz[idx * 3 + 0];
      float oy = sample_xyz[g * 3 + 1] - map_xyz[idx * 3 + 1];
      float oz = sample_xyz[g * 3 + 2] - map_xyz[idx * 3 + 2];
      wtbuf[sr] = __expf(-10.f * sqrtf(ox * ox + oy * oy + oz * oz));
    }
  };

  // L0: bf16 MFMA (K=96), epilogue quantizes H1 -> i8 (q1 = clamp(rint(lrelu(acc)*S1)))
  auto L0 = [&](const bf16_t* X, char* Qout) {
    f32x4 bi = *(const f32x4*)(sB0 + wid * 16 + q * 4);
    f32x4 acc[4] = {bi, bi, bi, bi};
    const bf16_t* rb = X + n * XSTR + q * 8;
    char* wb = Qout + n * QSTR + wid * 16 + q * 4;
    __builtin_amdgcn_s_setprio(1);
#pragma unroll
    for (int st = 0; st < 4; st++)
#pragma unroll
      for (int s = 0; s < 3; s++) {
        bf16x8 b = *(const bf16x8*)(rb + st * 16 * XSTR + s * 32);
        acc[st] = __builtin_amdgcn_mfma_f32_16x16x32_bf16(w0f[s], b, acc[st], 0, 0, 0);
      }
    __builtin_amdgcn_s_setprio(0);
#pragma unroll
    for (int st = 0; st < 4; st++) {
      unsigned u = 0;
#pragma unroll
      for (int i = 0; i < 4; i++) {
        float h = lrelu(acc[st][i]) * S1_Q;
        h = fminf(fmaxf(h, -127.f), 127.f);
        int iv = (int)rintf(h);
        u |= (unsigned)(iv & 255) << (8 * i);
      }
      *(unsigned*)(wb + st * 16 * QSTR) = u;
    }
  };

  // L1: i8 MFMA K=64 (2 B-frag reads per sample-tile), fused dequant+requant
  auto L1Q = [&](const char* Qin, char* Qout) {
    i32x4 acc[4] = {};
    const char* rb = Qin + n * QSTR + q * 16;
    char* wb = Qout + n * QSTR + wid * 16 + q * 4;
    f32x4 b1v = *(const f32x4*)(sB1 + wid * 16 + q * 4);   // pre-scaled by S2
    __builtin_amdgcn_s_setprio(1);
#pragma unroll
    for (int st = 0; st < 4; st++)
#pragma unroll
      for (int s = 0; s < 2; s++) {
        i32x4 b = *(const i32x4*)(rb + st * 16 * QSTR + s * 64);
        acc[st] = __builtin_amdgcn_mfma_i32_16x16x64_i8(w1q[s], b, acc[st], 0, 0, 0);
      }
    __builtin_amdgcn_s_setprio(0);
#pragma unroll
    for (int st = 0; st < 4; st++) {
      unsigned u = 0;
#pragma unroll
      for (int i = 0; i < 4; i++) {
        float v = fmaf((float)acc[st][i], DQ1S2, b1v[i]);   // = lrelu-arg * S2
        float h = fmaxf(v, 0.1f * v);
        h = fminf(fmaxf(h, -127.f), 127.f);
        int iv = (int)rintf(h);
        u |= (unsigned)(iv & 255) << (8 * i);
      }
      *(unsigned*)(wb + st * 16 * QSTR) = u;
    }
  };

  // L2: i8 MFMA K=64, dequant -> lrelu -> bf16 H3 (for fp32 KRED)
  auto L2Q = [&](const char* Qin, bf16_t* Hout) {
    i32x4 acc[4] = {};
    const char* rb = Qin + n * QSTR + q * 16;
    bf16_t* wb = Hout + n * HSTR + wid * 16 + q * 4;
    f32x4 b2v = *(const f32x4*)(sB2 + wid * 16 + q * 4);
    __builtin_amdgcn_s_setprio(1);
#pragma unroll
    for (int st = 0; st < 4; st++)
#pragma unroll
      for (int s = 0; s < 2; s++) {
        i32x4 b = *(const i32x4*)(rb + st * 16 * QSTR + s * 64);
        acc[st] = __builtin_amdgcn_mfma_i32_16x16x64_i8(w2q[s], b, acc[st], 0, 0, 0);
      }
    __builtin_amdgcn_s_setprio(0);
#pragma unroll
    for (int st = 0; st < 4; st++) {
      bf16x4 o;
#pragma unroll
      for (int i = 0; i < 4; i++) {
        float v = fmaf((float)acc[st][i], DQ2, b2v[i]);
        o[i] = (bf16_t)lrelu(v);
      }
      *(bf16x4*)(wb + st * 16 * HSTR) = o;
    }
  };

  auto KRED = [&](const bf16_t* Hin, const float* wt, const float* ws_, bf16_t* FS) {
    int g = tid >> 6;
    int c = (tid & 63) * 2;
    const bf16_t* kb = Hin + g * 8 * HSTR + c;
    float a0 = 0.f, a1 = 0.f;
#pragma unroll
    for (int k = 0; k < 8; k++) {
      float wk = wt[g * 8 + k];
      unsigned u = *(const unsigned*)(kb + k * HSTR);
      a0 += wk * __uint_as_float(u << 16);
      a1 += wk * __uint_as_float(u & 0xffff0000u);
    }
    float inv = 1.f / ws_[g];
    bf16x2 fo;
    fo[0] = (bf16_t)(a0 * inv);
    fo[1] = (bf16_t)(a1 * inv);
    *(bf16x2*)(FS + g * HSTR + c) = fo;
  };

  auto HEADS = [&](const bf16_t* FS, bf16_t* AR) {
    f32x4 ha = *(const f32x4*)(sBH + wid * 16 + q * 4);
    const bf16_t* rb = FS + n * HSTR + q * 8;
    __builtin_amdgcn_s_setprio(1);
#pragma unroll
    for (int s = 0; s < 4; s++) {
      bf16x8 b = *(const bf16x8*)(rb + s * 32);
      ha = __builtin_amdgcn_mfma_f32_16x16x32_bf16(hdf[s], b, ha, 0, 0, 0);
    }
    __builtin_amdgcn_s_setprio(0);
    if (n < 8) {
      const int base = (wid < 4) ? 64 : 0;    // a-vals high, r-vals low
      bf16x4 o;
      o[0] = (bf16_t)lrelu(ha[0]);
      o[1] = (bf16_t)lrelu(ha[1]);
      o[2] = (bf16_t)lrelu(ha[2]);
      o[3] = (bf16_t)lrelu(ha[3]);
      *(bf16x4*)(AR + n * HSTR + base + (wid & 3) * 16 + q * 4) = o;
    }
  };

  auto FINALS = [&](int tile) {
    if (wid == 0) {
      f32x4 c = *(const f32x4*)sFBv;
      const bf16_t* ab = sFB + l * 8;
      const bf16_t* rb = sAR + n * HSTR + q * 8;
#pragma unroll
      for (int s = 0; s < 4; s++) {
        bf16x8 a = *(const bf16x8*)(ab + s * 512);
        bf16x8 b = *(const bf16x8*)(rb + s * 32);
        c = __builtin_amdgcn_mfma_f32_16x16x32_bf16(a, b, c, 0, 0, 0);
      }
      if (q == 0 && n < 8) {
        float4 o;
        o.x = sigmoidf(c[0]);
        o.y = sigmoidf(c[1]);
        o.z = sigmoidf(c[2]);
        o.w = sigmoidf(c[3]);
        ((float4*)ar_out)[tile * 8 + n] = o;
      }
    }
  };

  // ---- one-time LDS init ----
  for (int i = tid; i < 8 * HSTR; i += 512) {
    sFS[8 * HSTR + i] = (bf16_t)0.f;
    sAR[8 * HSTR + i] = (bf16_t)0.f;
  }
  {
    int e0 = tid * 4;
    int jb = e0 & 7, ll = (e0 >> 3) & 63, s = e0 >> 9;
    int m = ll & 15;
#pragma unroll
    for (int ii = 0; ii < 4; ii++) {
      int k = s * 32 + (ll >> 4) * 8 + jb + ii;
      float v = 0.f;
      if (k < 64)  { if (m < 3) v = wr1g[k * 3 + m]; }
      else         { if (m == 3) v = wa1g[k - 64]; }
      sFB[e0 + ii] = (bf16_t)v;
    }
  }
  if (tid < 128)      sB0[tid] = b0g[tid];
  else if (tid < 256) sB1[tid - 128] = b1g[tid - 128] * S2_Q;   // pre-scaled for L1Q
  else if (tid < 384) sB2[tid - 256] = b2g[tid - 256];
  else { int t = tid - 384; sBH[t] = (t < 64) ? ba0g[t] : br0g[t - 64]; }
  if (tid < 4) sFBv[tid] = (tid < 3) ? br1g[tid] : ba1g[0];
  __syncthreads();

  // ---- dual-stream pipeline (champion schedule) ----
  for (int it = 0; it <= NIT; ++it) {
    const bool a_on = (it < NIT);
    const bool b_on = (it > 0);
    const int tA  = (int)blockIdx.x + (2 * it) * GRID;
    const int tAp = (int)blockIdx.x + (2 * it - 2) * GRID;
    const int tB  = (int)blockIdx.x + (2 * it + 1) * GRID;
    const int tBp = (int)blockIdx.x + (2 * it - 1) * GRID;

    // ---- p1: commitA(sX) | L2B(sQ2->sH3) | finalsA ----
    if (a_on) COMMIT(tA, sX, sWtA);
    if (b_on) L2Q(sQ2, sH3);
    if (b_on) FINALS(tAp);
    __syncthreads();

    // ---- p2: L0A(sX->sQ1) | kredB(sH3->sFS) | sWsA ----
    if (a_on) L0(sX, sQ1);
    if (b_on) KRED(sH3, sWtB, sWsB, sFS);
    if (a_on && tid < 8) {
      float ss = 0.f;
#pragma unroll
      for (int k = 0; k < 8; k++) ss += sWtA[tid * 8 + k];
      sWsA[tid] = ss;
    }
    __syncthreads();

    // ---- p3: L1A(sQ1->sQ2) | headsB(sFS->sAR) ----
    if (a_on) L1Q(sQ1, sQ2);
    if (b_on) HEADS(sFS, sAR);
    __syncthreads();

    // ---- p4: L2A(sQ2->sH3) | commitB(sX) | finalsB ----
    if (a_on) COMMIT(tB, sX, sWtB);
    if (a_on) L2Q(sQ2, sH3);
    if (b_on) FINALS(tBp);
    __syncthreads();

    if (it == NIT) break;   // drain complete (uniform exit)

    // ---- p5: kredA(sH3) | L0B(sX->sQ1) | sWsB ----
    L0(sX, sQ1);
    KRED(sH3, sWtA, sWsA, sFS);
    if (tid < 8) {
      float ss = 0.f;
#pragma unroll
      for (int k = 0; k < 8; k++) ss += sWtB[tid * 8 + k];
      sWsB[tid] = ss;
    }
    __syncthreads();

    // ---- p6: headsA(sFS->sAR) | L1B(sQ1->sQ2) ----
    L1Q(sQ1, sQ2);
    HEADS(sFS, sAR);
    __syncthreads();
  }
}

// ---------------------------------------------------------------------------
// Volume rendering (champion version, separate kernel)
// ---------------------------------------------------------------------------
__global__ __launch_bounds__(512)
void render_kernel(const float* __restrict__ ar, const float* __restrict__ dcam,
                   float* __restrict__ out) {
  int ray = blockIdx.x * 8 + (threadIdx.x >> 6);
  int s = threadIdx.x & 63;
  float4 v = ((const float4*)ar)[ray * 64 + s];
  float alpha = v.w;
  float t = 1.f - alpha + 1e-10f;
  float p = t;
#pragma unroll
  for (int d = 1; d < 64; d <<= 1) {
    float o = __shfl_up(p, d);
    if (s >= d) p *= o;
  }
  float pm1 = __shfl_up(p, 1);
  float T = (s == 0) ? 1.f : pm1;
  float bl = alpha * T;
  float dist = 1.f + 1.25f * dcam[ray * 64 + s];
  float cr = v.x * bl, cg = v.y * bl, cb = v.z * bl, cd = dist * bl, ca = bl;
#pragma unroll
  for (int d = 32; d > 0; d >>= 1) {
    cr += __shfl_xor(cr, d);
    cg += __shfl_xor(cg, d);
    cb += __shfl_xor(cb, d);
    cd += __shfl_xor(cd, d);
    ca += __shfl_xor(ca, d);
  }
  if (s == 0) {
    out[ray * 5 + 0] = cr; out[ray * 5 + 1] = cg; out[ray * 5 + 2] = cb;
    out[ray * 5 + 3] = cd; out[ray * 5 + 4] = ca;
  }
}

// ---------------------------------------------------------------------------
extern "C" void kernel_launch(void* const* d_in, const int* in_sizes, int n_in,
                              void* d_out, int out_size, void* d_ws, size_t ws_size,
                              hipStream_t stream) {
  const float* map_xyz    = (const float*)d_in[0];
  const float* map_feat   = (const float*)d_in[1];
  const int*   ind        = (const int*)d_in[2];
  const float* sample_xyz = (const float*)d_in[3];
  const float* dist_cam   = (const float*)d_in[4];
  const float* W0  = (const float*)d_in[5];
  const float* b0  = (const float*)d_in[6];
  const float* W1  = (const float*)d_in[7];
  const float* b1  = (const float*)d_in[8];
  const float* W2  = (const float*)d_in[9];
  const float* b2  = (const float*)d_in[10];
  const float* Wa0 = (const float*)d_in[11];
  const float* ba0 = (const float*)d_in[12];
  const float* Wa1 = (const float*)d_in[13];
  const float* ba1 = (const float*)d_in[14];
  const float* Wr0 = (const float*)d_in[15];
  const float* br0 = (const float*)d_in[16];
  const float* Wr1 = (const float*)d_in[17];
  const float* br1 = (const float*)d_in[18];

  bf16_t* wpack = (bf16_t*)d_ws;
  char*   wq    = (char*)d_ws + PKQ_OFF;
  float*  ar    = (float*)((char*)d_ws + WS_AR_BYTES);

  pack_weights<<<240, 256, 0, stream>>>(W0, W1, W2, Wa0, Wr0, wpack);
  pack_w12_i8<<<128, 256, 0, stream>>>(W1, W2, wq);
  nerf_main<<<GRID, 512, 0, stream>>>(map_xyz, map_feat, ind, sample_xyz,
                                      b0, b1, b2, ba0, Wa1, ba1, br0, Wr1, br1,
                                      wpack, ar);
  render_kernel<<<256, 512, 0, stream>>>(ar, dist_cam, (float*)d_out);
}

// Round 9
// 357.896 us; speedup vs baseline: 1.2117x; 1.0440x over previous
//
#include <hip/hip_runtime.h>

typedef __bf16 bf16_t;
typedef __bf16 bf16x2 __attribute__((ext_vector_type(2)));
typedef __bf16 bf16x4 __attribute__((ext_vector_type(4)));
typedef __bf16 bf16x8 __attribute__((ext_vector_type(8)));
typedef float  f32x4  __attribute__((ext_vector_type(4)));
typedef int    i32x4  __attribute__((ext_vector_type(4)));

#define NPIX 2048
#define NS   64
#define NK   8
#define NSAMP (NPIX*NS)          // 131072
#define NROWS (NSAMP*NK)         // 1048576
#define TROWS 64
#define NTILES (NROWS/TROWS)     // 16384
#define GRID   512
#define NIT    16                // 32 tiles/block = 16 A + 16 B (strided, champion)
#define XSTR 104                 // 96 cols + 8 pad (bf16), rows 16B-aligned
#define HSTR 136                 // bf16 H3 buffer (champion value)
#define QSTR 144                 // i8 H1/H2 rows: 16B-aligned, 36dw ≡ 4 mod 32 (2-way, free)

// packed bf16 weight fragment bases (in bf16x8 units) — unchanged
#define PK_W0 0
#define PK_W1 1536
#define PK_W2 3584
#define PK_WA 5632
#define PK_WR 6656
#define PK_TOT 7680

#define PKQ_OFF   122880         // byte offset of i8 W1/W2 packs in workspace
#define WS_AR_BYTES (122880 + 32768)   // ar after the 2x16KB i8 packs

// ---- i8 quantization scales (validated R8: absmax stayed at bf16 noise floor) ----
#define SW_Q 300.0f              // W1/W2 weight scale
#define S1_Q 62.0f               // H1 activation scale (pre-folded into W0/b0 now)
#define S2_Q 87.0f               // H2 activation scale
#define DQ1S2 (S2_Q / (S1_Q * SW_Q))   // L1 acc -> S2 units (lrelu homogeneous)
#define DQ2   (1.0f / (S2_Q * SW_Q))   // L2 acc -> f32
#define RMAGIC 12582912.f        // 1.5*2^23: +RMAGIC = RNE round, int8 in mantissa low byte

// ---------------------------------------------------------------------------
// bf16 pack. Round-9: W0 section pre-scaled by S1_Q (lrelu homogeneity) so the
// L0 epilogue's *S1 multiply disappears; b0 likewise scaled at LDS init.
// ---------------------------------------------------------------------------
__global__ void pack_weights(const float* __restrict__ W0, const float* __restrict__ W1,
                             const float* __restrict__ W2, const float* __restrict__ Wa0,
                             const float* __restrict__ Wr0, bf16_t* __restrict__ dst0) {
  int tid = blockIdx.x * blockDim.x + threadIdx.x;
  if (tid >= PK_TOT * 8) return;
  const float* src; bf16_t* dst; int e, KD, ND, KS; float scl = 1.f;
  if (tid < 12288)      { src = W0;  dst = dst0;         e = tid;         KD = 88;  ND = 128; KS = 3; scl = S1_Q; }
  else if (tid < 28672) { src = W1;  dst = dst0 + 12288; e = tid - 12288; KD = 128; ND = 128; KS = 4; }
  else if (tid < 45056) { src = W2;  dst = dst0 + 28672; e = tid - 28672; KD = 128; ND = 128; KS = 4; }
  else if (tid < 53248) { src = Wa0; dst = dst0 + 45056; e = tid - 45056; KD = 128; ND = 64;  KS = 4; }
  else                  { src = Wr0; dst = dst0 + 53248; e = tid - 53248; KD = 128; ND = 64;  KS = 4; }
  int j = e & 7, l = (e >> 3) & 63, f = e >> 9;
  int s = f % KS, t = f / KS;
  int row = s * 32 + (l >> 4) * 8 + j;
  int col = t * 16 + (l & 15);
  float v = (row < KD) ? src[row * ND + col] * scl : 0.f;
  dst[e] = (bf16_t)v;
}

// ---------------------------------------------------------------------------
// i8 pack for W1/W2 (unchanged from R8; A/B layout-symmetry argument verified)
// ---------------------------------------------------------------------------
__global__ void pack_w12_i8(const float* __restrict__ W1, const float* __restrict__ W2,
                            char* __restrict__ dstq) {
  int tid = blockIdx.x * blockDim.x + threadIdx.x;
  if (tid >= 2 * 16384) return;
  const float* src = (tid < 16384) ? W1 : W2;
  int e = tid & 16383;
  int j = e & 15, l = (e >> 4) & 63, f = e >> 10;
  int s = f & 1, t = f >> 1;
  int k = s * 64 + ((l >> 4) << 4) + j;
  int c = t * 16 + (l & 15);
  int iv = (int)rintf(src[k * 128 + c] * SW_Q);
  iv = iv > 127 ? 127 : (iv < -127 ? -127 : iv);
  dstq[tid] = (char)iv;
}

__device__ __forceinline__ float lrelu(float v) { return fmaxf(v, 0.1f * v); }
__device__ __forceinline__ float sigmoidf(float x) { return 1.f / (1.f + __expf(-x)); }

// lrelu -> clamp -> RNE-round-to-int8-in-low-byte (magic), numerics ==
// rintf+clamp of R8. One add replaces rndne+cvt; perm replaces and/shl/or.
__device__ __forceinline__ float q8pre(float v) {
  float h = fmaxf(v, 0.1f * v);
  h = fminf(fmaxf(h, -127.f), 127.f);
  return h + RMAGIC;
}
__device__ __forceinline__ unsigned pack4(float r0, float r1, float r2, float r3) {
  unsigned t0 = __builtin_amdgcn_perm(__builtin_bit_cast(unsigned, r1),
                                      __builtin_bit_cast(unsigned, r0), 0x00000400u);
  unsigned t1 = __builtin_amdgcn_perm(__builtin_bit_cast(unsigned, r3),
                                      __builtin_bit_cast(unsigned, r2), 0x00000400u);
  return __builtin_amdgcn_perm(t1, t0, 0x05040100u);
}

// ---------------------------------------------------------------------------
// Round-15 (R9): EPILOGUE VALU DIET on the R8 i8 structure.
// R8 validated the LDS-instruction wall model (predicted 205-218, got 212) and
// re-exposed VALU as the top pipe (55%). Epilogues are ~400 of ~500 VALU
// instr/wave/tile. Cuts (numerics-identical): W0/b0 pre-scaled by S1 (kills
// *S1 mul), magic-constant RNE round (kills v_rndne+v_cvt), v_perm byte pack
// (kills and/shl/or chain), med3 clamp. L0 9.5->4.75, L1Q 10.5->6.75 per elem.
// Everything else unchanged from R8.
// ---------------------------------------------------------------------------
__global__ __launch_bounds__(512, 4)
void nerf_main(const float* __restrict__ map_xyz, const float* __restrict__ map_feat,
               const int* __restrict__ ind, const float* __restrict__ sample_xyz,
               const float* __restrict__ b0g, const float* __restrict__ b1g,
               const float* __restrict__ b2g, const float* __restrict__ ba0g,
               const float* __restrict__ wa1g, const float* __restrict__ ba1g,
               const float* __restrict__ br0g, const float* __restrict__ wr1g,
               const float* __restrict__ br1g, const bf16_t* __restrict__ wpack,
               float* __restrict__ ar_out)
{
  __shared__ __align__(16) bf16_t sX[TROWS * XSTR];     // X (bf16)
  __shared__ __align__(16) char   sQ1[TROWS * QSTR];    // H1 (i8)
  __shared__ __align__(16) char   sQ2[TROWS * QSTR];    // H2 (i8)
  __shared__ __align__(16) bf16_t sH3[TROWS * HSTR];    // H3 (bf16, for KRED)
  __shared__ __align__(16) bf16_t sFS[16 * HSTR];       // feat_s (rows 8..15 zero)
  __shared__ __align__(16) bf16_t sAR[16 * HSTR];       // [r|a] (rows 8..15 zero)
  __shared__ __align__(16) bf16_t sFB[2048];            // finals A-frags
  __shared__ __align__(16) float sWtA[TROWS], sWtB[TROWS];
  __shared__ float sWsA[8], sWsB[8];
  __shared__ __align__(16) float sB0[128], sB1[128], sB2[128], sBH[128], sFBv[4];

  const int tid = threadIdx.x;
  const int wid = tid >> 6, l = tid & 63;
  const int q = l >> 4, n = l & 15;
  const int sr = tid >> 3, sp = tid & 7;   // staging thread coords

  // ---- persistent weights: W0/heads bf16 A-frags, W1/W2 i8 A-frags ----
  const bf16x8* pk = (const bf16x8*)wpack;
  bf16x8 w0f[3], hdf[4];
#pragma unroll
  for (int s = 0; s < 3; s++) w0f[s] = pk[PK_W0 + (wid * 3 + s) * 64 + l];
#pragma unroll
  for (int s = 0; s < 4; s++)
    hdf[s] = pk[(wid < 4 ? PK_WA : PK_WR) + ((wid & 3) * 4 + s) * 64 + l];
  const i32x4* pq = (const i32x4*)((const char*)wpack + PKQ_OFF);
  i32x4 w1q[2], w2q[2];
#pragma unroll
  for (int s = 0; s < 2; s++) {
    w1q[s] = pq[(wid * 2 + s) * 64 + l];
    w2q[s] = pq[1024 + (wid * 2 + s) * 64 + l];
  }

  // ---- phase ops ----
  auto COMMIT = [&](int tile, bf16_t* X, float* wtbuf) {
    const int m = tile * TROWS + sr;
    const int idx = ind[m];
    const float4* fp = (const float4*)(map_feat + (size_t)idx * 64 + sp * 8);
    float4 f0 = fp[0], f1 = fp[1];
    bf16x8 v;
    v[0] = (bf16_t)f0.x; v[1] = (bf16_t)f0.y; v[2] = (bf16_t)f0.z; v[3] = (bf16_t)f0.w;
    v[4] = (bf16_t)f1.x; v[5] = (bf16_t)f1.y; v[6] = (bf16_t)f1.z; v[7] = (bf16_t)f1.w;
    *(bf16x8*)(X + sr * XSTR + sp * 8) = v;
    const int g = m >> 3;
    if (sp < 6) {
      const int d = sp >> 1;
      float o = sample_xyz[g * 3 + d] - map_xyz[idx * 3 + d];
      float s1 = __sinf(o), c1 = __cosf(o);
      float s2 = 2.f * s1 * c1, c2 = 1.f - 2.f * s1 * s1;
      float s4 = 2.f * s2 * c2, c4 = 1.f - 2.f * s2 * s2;
      float s8 = 2.f * s4 * c4, c8 = 1.f - 2.f * s4 * s4;
      bf16x4 e;
      if (sp & 1) { e[0] = (bf16_t)c1; e[1] = (bf16_t)c2; e[2] = (bf16_t)c4; e[3] = (bf16_t)c8; }
      else        { e[0] = (bf16_t)s1; e[1] = (bf16_t)s2; e[2] = (bf16_t)s4; e[3] = (bf16_t)s8; }
      *(bf16x4*)(X + sr * XSTR + 64 + d * 8 + (sp & 1) * 4) = e;
    } else if (sp == 6) {
      bf16x8 z = {};
      *(bf16x8*)(X + sr * XSTR + 88) = z;   // pad cols 88..95 (zero k-rows)
    } else {
      float ox = sample_xyz[g * 3 + 0] - map_xyz[idx * 3 + 0];
      float oy = sample_xyz[g * 3 + 1] - map_xyz[idx * 3 + 1];
      float oz = sample_xyz[g * 3 + 2] - map_xyz[idx * 3 + 2];
      wtbuf[sr] = __expf(-10.f * sqrtf(ox * ox + oy * oy + oz * oz));
    }
  };

  // L0: bf16 MFMA (K=96); W0/b0 pre-scaled by S1 -> acc IS the quant value
  auto L0 = [&](const bf16_t* X, char* Qout) {
    f32x4 bi = *(const f32x4*)(sB0 + wid * 16 + q * 4);   // pre-scaled by S1
    f32x4 acc[4] = {bi, bi, bi, bi};
    const bf16_t* rb = X + n * XSTR + q * 8;
    char* wb = Qout + n * QSTR + wid * 16 + q * 4;
    __builtin_amdgcn_s_setprio(1);
#pragma unroll
    for (int st = 0; st < 4; st++)
#pragma unroll
      for (int s = 0; s < 3; s++) {
        bf16x8 b = *(const bf16x8*)(rb + st * 16 * XSTR + s * 32);
        acc[st] = __builtin_amdgcn_mfma_f32_16x16x32_bf16(w0f[s], b, acc[st], 0, 0, 0);
      }
    __builtin_amdgcn_s_setprio(0);
#pragma unroll
    for (int st = 0; st < 4; st++) {
      float r0 = q8pre(acc[st][0]), r1 = q8pre(acc[st][1]);
      float r2 = q8pre(acc[st][2]), r3 = q8pre(acc[st][3]);
      *(unsigned*)(wb + st * 16 * QSTR) = pack4(r0, r1, r2, r3);
    }
  };

  // L1: i8 MFMA K=64, fused dequant+requant (magic-round + perm pack)
  auto L1Q = [&](const char* Qin, char* Qout) {
    i32x4 acc[4] = {};
    const char* rb = Qin + n * QSTR + q * 16;
    char* wb = Qout + n * QSTR + wid * 16 + q * 4;
    f32x4 b1v = *(const f32x4*)(sB1 + wid * 16 + q * 4);   // pre-scaled by S2
    __builtin_amdgcn_s_setprio(1);
#pragma unroll
    for (int st = 0; st < 4; st++)
#pragma unroll
      for (int s = 0; s < 2; s++) {
        i32x4 b = *(const i32x4*)(rb + st * 16 * QSTR + s * 64);
        acc[st] = __builtin_amdgcn_mfma_i32_16x16x64_i8(w1q[s], b, acc[st], 0, 0, 0);
      }
    __builtin_amdgcn_s_setprio(0);
#pragma unroll
    for (int st = 0; st < 4; st++) {
      float r[4];
#pragma unroll
      for (int i = 0; i < 4; i++)
        r[i] = q8pre(fmaf((float)acc[st][i], DQ1S2, b1v[i]));
      *(unsigned*)(wb + st * 16 * QSTR) = pack4(r[0], r[1], r[2], r[3]);
    }
  };

  // L2: i8 MFMA K=64, dequant -> lrelu -> bf16 H3 (for fp32 KRED)
  auto L2Q = [&](const char* Qin, bf16_t* Hout) {
    i32x4 acc[4] = {};
    const char* rb = Qin + n * QSTR + q * 16;
    bf16_t* wb = Hout + n * HSTR + wid * 16 + q * 4;
    f32x4 b2v = *(const f32x4*)(sB2 + wid * 16 + q * 4);
    __builtin_amdgcn_s_setprio(1);
#pragma unroll
    for (int st = 0; st < 4; st++)
#pragma unroll
      for (int s = 0; s < 2; s++) {
        i32x4 b = *(const i32x4*)(rb + st * 16 * QSTR + s * 64);
        acc[st] = __builtin_amdgcn_mfma_i32_16x16x64_i8(w2q[s], b, acc[st], 0, 0, 0);
      }
    __builtin_amdgcn_s_setprio(0);
#pragma unroll
    for (int st = 0; st < 4; st++) {
      bf16x4 o;
#pragma unroll
      for (int i = 0; i < 4; i++) {
        float v = fmaf((float)acc[st][i], DQ2, b2v[i]);
        o[i] = (bf16_t)lrelu(v);
      }
      *(bf16x4*)(wb + st * 16 * HSTR) = o;
    }
  };

  auto KRED = [&](const bf16_t* Hin, const float* wt, const float* ws_, bf16_t* FS) {
    int g = tid >> 6;
    int c = (tid & 63) * 2;
    const bf16_t* kb = Hin + g * 8 * HSTR + c;
    float a0 = 0.f, a1 = 0.f;
#pragma unroll
    for (int k = 0; k < 8; k++) {
      float wk = wt[g * 8 + k];
      unsigned u = *(const unsigned*)(kb + k * HSTR);
      a0 += wk * __uint_as_float(u << 16);
      a1 += wk * __uint_as_float(u & 0xffff0000u);
    }
    float inv = 1.f / ws_[g];
    bf16x2 fo;
    fo[0] = (bf16_t)(a0 * inv);
    fo[1] = (bf16_t)(a1 * inv);
    *(bf16x2*)(FS + g * HSTR + c) = fo;
  };

  auto HEADS = [&](const bf16_t* FS, bf16_t* AR) {
    f32x4 ha = *(const f32x4*)(sBH + wid * 16 + q * 4);
    const bf16_t* rb = FS + n * HSTR + q * 8;
    __builtin_amdgcn_s_setprio(1);
#pragma unroll
    for (int s = 0; s < 4; s++) {
      bf16x8 b = *(const bf16x8*)(rb + s * 32);
      ha = __builtin_amdgcn_mfma_f32_16x16x32_bf16(hdf[s], b, ha, 0, 0, 0);
    }
    __builtin_amdgcn_s_setprio(0);
    if (n < 8) {
      const int base = (wid < 4) ? 64 : 0;    // a-vals high, r-vals low
      bf16x4 o;
      o[0] = (bf16_t)lrelu(ha[0]);
      o[1] = (bf16_t)lrelu(ha[1]);
      o[2] = (bf16_t)lrelu(ha[2]);
      o[3] = (bf16_t)lrelu(ha[3]);
      *(bf16x4*)(AR + n * HSTR + base + (wid & 3) * 16 + q * 4) = o;
    }
  };

  auto FINALS = [&](int tile) {
    if (wid == 0) {
      f32x4 c = *(const f32x4*)sFBv;
      const bf16_t* ab = sFB + l * 8;
      const bf16_t* rb = sAR + n * HSTR + q * 8;
#pragma unroll
      for (int s = 0; s < 4; s++) {
        bf16x8 a = *(const bf16x8*)(ab + s * 512);
        bf16x8 b = *(const bf16x8*)(rb + s * 32);
        c = __builtin_amdgcn_mfma_f32_16x16x32_bf16(a, b, c, 0, 0, 0);
      }
      if (q == 0 && n < 8) {
        float4 o;
        o.x = sigmoidf(c[0]);
        o.y = sigmoidf(c[1]);
        o.z = sigmoidf(c[2]);
        o.w = sigmoidf(c[3]);
        ((float4*)ar_out)[tile * 8 + n] = o;
      }
    }
  };

  // ---- one-time LDS init ----
  for (int i = tid; i < 8 * HSTR; i += 512) {
    sFS[8 * HSTR + i] = (bf16_t)0.f;
    sAR[8 * HSTR + i] = (bf16_t)0.f;
  }
  {
    int e0 = tid * 4;
    int jb = e0 & 7, ll = (e0 >> 3) & 63, s = e0 >> 9;
    int m = ll & 15;
#pragma unroll
    for (int ii = 0; ii < 4; ii++) {
      int k = s * 32 + (ll >> 4) * 8 + jb + ii;
      float v = 0.f;
      if (k < 64)  { if (m < 3) v = wr1g[k * 3 + m]; }
      else         { if (m == 3) v = wa1g[k - 64]; }
      sFB[e0 + ii] = (bf16_t)v;
    }
  }
  if (tid < 128)      sB0[tid] = b0g[tid] * S1_Q;               // pre-scaled for L0
  else if (tid < 256) sB1[tid - 128] = b1g[tid - 128] * S2_Q;   // pre-scaled for L1Q
  else if (tid < 384) sB2[tid - 256] = b2g[tid - 256];
  else { int t = tid - 384; sBH[t] = (t < 64) ? ba0g[t] : br0g[t - 64]; }
  if (tid < 4) sFBv[tid] = (tid < 3) ? br1g[tid] : ba1g[0];
  __syncthreads();

  // ---- dual-stream pipeline (champion schedule) ----
  for (int it = 0; it <= NIT; ++it) {
    const bool a_on = (it < NIT);
    const bool b_on = (it > 0);
    const int tA  = (int)blockIdx.x + (2 * it) * GRID;
    const int tAp = (int)blockIdx.x + (2 * it - 2) * GRID;
    const int tB  = (int)blockIdx.x + (2 * it + 1) * GRID;
    const int tBp = (int)blockIdx.x + (2 * it - 1) * GRID;

    // ---- p1: commitA(sX) | L2B(sQ2->sH3) | finalsA ----
    if (a_on) COMMIT(tA, sX, sWtA);
    if (b_on) L2Q(sQ2, sH3);
    if (b_on) FINALS(tAp);
    __syncthreads();

    // ---- p2: L0A(sX->sQ1) | kredB(sH3->sFS) | sWsA ----
    if (a_on) L0(sX, sQ1);
    if (b_on) KRED(sH3, sWtB, sWsB, sFS);
    if (a_on && tid < 8) {
      float ss = 0.f;
#pragma unroll
      for (int k = 0; k < 8; k++) ss += sWtA[tid * 8 + k];
      sWsA[tid] = ss;
    }
    __syncthreads();

    // ---- p3: L1A(sQ1->sQ2) | headsB(sFS->sAR) ----
    if (a_on) L1Q(sQ1, sQ2);
    if (b_on) HEADS(sFS, sAR);
    __syncthreads();

    // ---- p4: L2A(sQ2->sH3) | commitB(sX) | finalsB ----
    if (a_on) COMMIT(tB, sX, sWtB);
    if (a_on) L2Q(sQ2, sH3);
    if (b_on) FINALS(tBp);
    __syncthreads();

    if (it == NIT) break;   // drain complete (uniform exit)

    // ---- p5: kredA(sH3) | L0B(sX->sQ1) | sWsB ----
    L0(sX, sQ1);
    KRED(sH3, sWtA, sWsA, sFS);
    if (tid < 8) {
      float ss = 0.f;
#pragma unroll
      for (int k = 0; k < 8; k++) ss += sWtB[tid * 8 + k];
      sWsB[tid] = ss;
    }
    __syncthreads();

    // ---- p6: headsA(sFS->sAR) | L1B(sQ1->sQ2) ----
    L1Q(sQ1, sQ2);
    HEADS(sFS, sAR);
    __syncthreads();
  }
}

// ---------------------------------------------------------------------------
// Volume rendering (champion version, separate kernel)
// ---------------------------------------------------------------------------
__global__ __launch_bounds__(512)
void render_kernel(const float* __restrict__ ar, const float* __restrict__ dcam,
                   float* __restrict__ out) {
  int ray = blockIdx.x * 8 + (threadIdx.x >> 6);
  int s = threadIdx.x & 63;
  float4 v = ((const float4*)ar)[ray * 64 + s];
  float alpha = v.w;
  float t = 1.f - alpha + 1e-10f;
  float p = t;
#pragma unroll
  for (int d = 1; d < 64; d <<= 1) {
    float o = __shfl_up(p, d);
    if (s >= d) p *= o;
  }
  float pm1 = __shfl_up(p, 1);
  float T = (s == 0) ? 1.f : pm1;
  float bl = alpha * T;
  float dist = 1.f + 1.25f * dcam[ray * 64 + s];
  float cr = v.x * bl, cg = v.y * bl, cb = v.z * bl, cd = dist * bl, ca = bl;
#pragma unroll
  for (int d = 32; d > 0; d >>= 1) {
    cr += __shfl_xor(cr, d);
    cg += __shfl_xor(cg, d);
    cb += __shfl_xor(cb, d);
    cd += __shfl_xor(cd, d);
    ca += __shfl_xor(ca, d);
  }
  if (s == 0) {
    out[ray * 5 + 0] = cr; out[ray * 5 + 1] = cg; out[ray * 5 + 2] = cb;
    out[ray * 5 + 3] = cd; out[ray * 5 + 4] = ca;
  }
}

// ---------------------------------------------------------------------------
extern "C" void kernel_launch(void* const* d_in, const int* in_sizes, int n_in,
                              void* d_out, int out_size, void* d_ws, size_t ws_size,
                              hipStream_t stream) {
  const float* map_xyz    = (const float*)d_in[0];
  const float* map_feat   = (const float*)d_in[1];
  const int*   ind        = (const int*)d_in[2];
  const float* sample_xyz = (const float*)d_in[3];
  const float* dist_cam   = (const float*)d_in[4];
  const float* W0  = (const float*)d_in[5];
  const float* b0  = (const float*)d_in[6];
  const float* W1  = (const float*)d_in[7];
  const float* b1  = (const float*)d_in[8];
  const float* W2  = (const float*)d_in[9];
  const float* b2  = (const float*)d_in[10];
  const float* Wa0 = (const float*)d_in[11];
  const float* ba0 = (const float*)d_in[12];
  const float* Wa1 = (const float*)d_in[13];
  const float* ba1 = (const float*)d_in[14];
  const float* Wr0 = (const float*)d_in[15];
  const float* br0 = (const float*)d_in[16];
  const float* Wr1 = (const float*)d_in[17];
  const float* br1 = (const float*)d_in[18];

  bf16_t* wpack = (bf16_t*)d_ws;
  char*   wq    = (char*)d_ws + PKQ_OFF;
  float*  ar    = (float*)((char*)d_ws + WS_AR_BYTES);

  pack_weights<<<240, 256, 0, stream>>>(W0, W1, W2, Wa0, Wr0, wpack);
  pack_w12_i8<<<128, 256, 0, stream>>>(W1, W2, wq);
  nerf_main<<<GRID, 512, 0, stream>>>(map_xyz, map_feat, ind, sample_xyz,
                                      b0, b1, b2, ba0, Wa1, ba1, br0, Wr1, br1,
                                      wpack, ar);
  render_kernel<<<256, 512, 0, stream>>>(ar, dist_cam, (float*)d_out);
}